// Round 4
// baseline (2383.232 us; speedup 1.0000x reference)
//
#include <hip/hip_runtime.h>
#include <hip/hip_bf16.h>

typedef __hip_bfloat16 bft;

#define BLK 256
static constexpr int Cc = 192;     // channels
static constexpr int L  = 192;     // H = W
static constexpr int S  = 36864;   // L*L
static constexpr int Bn = 2;       // batch
static constexpr int HID = 510;    // int(192*2.66)
static constexpr int PW = 50;      // FFN strip width incl. halo
static constexpr int SW = 48;      // FFN strip output width
static constexpr double PI_D = 3.141592653589793238462643383279502884;

__device__ __forceinline__ float ldf(const float* p) { return *p; }
__device__ __forceinline__ float ldf(const bft* p)   { return __bfloat162float(*p); }
__device__ __forceinline__ void  stf(float* p, float v) { *p = v; }
__device__ __forceinline__ void  stf(bft* p, float v)   { *p = __float2bfloat16(v); }

// ---------------- DCT matrix init (orthonormal DCT-II, Mh == Mw) -------------
__global__ __launch_bounds__(BLK) void k_dct_init(float* __restrict__ dct) {
    int idx = blockIdx.x * BLK + threadIdx.x;
    if (idx >= L * L) return;
    int p = idx / L, h = idx - p * L;
    double v = (p == 0) ? sqrt(1.0 / L)
                        : cos(PI_D * p * (2 * h + 1) / (2.0 * L)) * sqrt(2.0 / L);
    dct[idx] = (float)v;
}

// ---------------- LayerNorm over channel dim (per batch) ---------------------
template <typename TI>
__global__ __launch_bounds__(BLK) void k_ln(const TI* __restrict__ x,
                                            const float* __restrict__ w,
                                            const float* __restrict__ b,
                                            bft* __restrict__ out) {
    int s = blockIdx.x * BLK + threadIdx.x;   // [0, S)
    const TI* xp = x + s;
    float sum = 0.f, sq = 0.f;
    for (int c = 0; c < Cc; ++c) {
        float v = ldf(xp + (size_t)c * S);
        sum += v; sq += v * v;
    }
    float mu = sum * (1.f / Cc);
    float var = sq * (1.f / Cc) - mu * mu;
    float r = rsqrtf(var + 1e-5f);
    for (int c = 0; c < Cc; ++c) {
        float v = ldf(xp + (size_t)c * S);
        stf(out + s + (size_t)c * S, (v - mu) * r * w[c] + b[c]);
    }
}

// ---------------- batched 192x192 transform GEMM (per batch, bf16 imgs) ------
// MODE 0: A=dct,  B=img          (t = Mh @ Y)
// MODE 1: A=img,  B=dct^T        (yd = T @ Mw^T)
// MODE 2: A=img,  B=dct          (u = P @ Mw)
// MODE 3: A=dct^T,B=img          (out = Mh^T @ U) [+ optional fp32 residual]
template <int MODE, bool RESID>
__global__ __launch_bounds__(BLK) void k_transform(const float* __restrict__ dct,
                                                   const bft* __restrict__ img_in,
                                                   bft* __restrict__ img_out,
                                                   const float* __restrict__ resid) {
    __shared__ float As[16][68];
    __shared__ float Bs[16][68];
    const int tid = threadIdx.x;
    const int tx = tid & 15, ty = tid >> 4;
    const int m0 = blockIdx.y * 64, n0 = blockIdx.x * 64;
    const size_t zoff = (size_t)blockIdx.z * S;
    const bft* imgp = img_in + zoff;
    float acc[4][4] = {{0.f}};
    for (int k0 = 0; k0 < L; k0 += 16) {
#pragma unroll
        for (int i = 0; i < 4; ++i) {
            int idx = i * BLK + tid;
            if (MODE == 3) {
                int m = idx & 63, kk = idx >> 6;
                As[kk][m] = dct[(size_t)(k0 + kk) * L + m0 + m];
            } else if (MODE == 0) {
                int kk = idx & 15, m = idx >> 4;
                As[kk][m] = dct[(size_t)(m0 + m) * L + k0 + kk];
            } else {
                int kk = idx & 15, m = idx >> 4;
                As[kk][m] = ldf(imgp + (size_t)(m0 + m) * L + k0 + kk);
            }
        }
#pragma unroll
        for (int i = 0; i < 4; ++i) {
            int idx = i * BLK + tid;
            if (MODE == 1) {
                int kk = idx & 15, n = idx >> 4;
                Bs[kk][n] = dct[(size_t)(n0 + n) * L + k0 + kk];
            } else if (MODE == 2) {
                int n = idx & 63, kk = idx >> 6;
                Bs[kk][n] = dct[(size_t)(k0 + kk) * L + n0 + n];
            } else {
                int n = idx & 63, kk = idx >> 6;
                Bs[kk][n] = ldf(imgp + (size_t)(k0 + kk) * L + n0 + n);
            }
        }
        __syncthreads();
#pragma unroll
        for (int kk = 0; kk < 16; ++kk) {
            float a[4], bv[4];
#pragma unroll
            for (int i = 0; i < 4; ++i) a[i] = As[kk][ty * 4 + i];
#pragma unroll
            for (int j = 0; j < 4; ++j) bv[j] = Bs[kk][tx * 4 + j];
#pragma unroll
            for (int i = 0; i < 4; ++i)
#pragma unroll
                for (int j = 0; j < 4; ++j) acc[i][j] += a[i] * bv[j];
        }
        __syncthreads();
    }
    bft* op = img_out + zoff;
#pragma unroll
    for (int i = 0; i < 4; ++i) {
        int m = m0 + ty * 4 + i;
#pragma unroll
        for (int j = 0; j < 4; ++j) {
            int n = n0 + tx * 4 + j;
            float v = acc[i][j];
            if constexpr (RESID) v += resid[zoff + (size_t)m * L + n];
            stf(op + (size_t)m * L + n, v);
        }
    }
}

// ---------------- conv1x1 GEMM (per batch): out[m,s] = sum_k W[m,k] in[k,s] --
template <bool BIAS>
__global__ __launch_bounds__(BLK) void k_conv1x1(const float* __restrict__ Wm,
                                                 const bft* __restrict__ In,
                                                 bft* __restrict__ Out,
                                                 const float* __restrict__ bias,
                                                 int M, int K) {
    __shared__ float As[16][68];
    __shared__ float Bs[16][68];
    const int tid = threadIdx.x;
    const int tx = tid & 15, ty = tid >> 4;
    const int n0 = blockIdx.x * 64, m0 = blockIdx.y * 64;
    float acc[4][4] = {{0.f}};
    for (int k0 = 0; k0 < K; k0 += 16) {
#pragma unroll
        for (int i = 0; i < 4; ++i) {
            int idx = i * BLK + tid;
            int kk = idx & 15, m = idx >> 4;
            int gm = m0 + m, gk = k0 + kk;
            float v = 0.f;
            if (gm < M && gk < K) v = Wm[(size_t)gm * K + gk];
            As[kk][m] = v;
        }
#pragma unroll
        for (int i = 0; i < 4; ++i) {
            int idx = i * BLK + tid;
            int n = idx & 63, kk = idx >> 6;
            int gk = k0 + kk;
            float v = 0.f;
            if (gk < K) v = ldf(In + (size_t)gk * S + n0 + n);
            Bs[kk][n] = v;
        }
        __syncthreads();
#pragma unroll
        for (int kk = 0; kk < 16; ++kk) {
            float a[4], bv[4];
#pragma unroll
            for (int i = 0; i < 4; ++i) a[i] = As[kk][ty * 4 + i];
#pragma unroll
            for (int j = 0; j < 4; ++j) bv[j] = Bs[kk][tx * 4 + j];
#pragma unroll
            for (int i = 0; i < 4; ++i)
#pragma unroll
                for (int j = 0; j < 4; ++j) acc[i][j] += a[i] * bv[j];
        }
        __syncthreads();
    }
#pragma unroll
    for (int i = 0; i < 4; ++i) {
        int m = m0 + ty * 4 + i;
        if (m >= M) continue;
        float bi = 0.f;
        if constexpr (BIAS) bi = bias[m];
#pragma unroll
        for (int j = 0; j < 4; ++j) {
            int n = n0 + tx * 4 + j;
            stf(Out + (size_t)m * S + n, acc[i][j] + bi);
        }
    }
}

// ---------------- window channel attention with fused depthwise 3x3 ----------
// one block per (window, head); qkv is this batch's [576][S] bf16
__global__ __launch_bounds__(BLK) void k_attn(const bft* __restrict__ qkv,
                                              const float* __restrict__ w_dw,
                                              const float* __restrict__ temp,
                                              bft* __restrict__ outp) {
    __shared__ float qs[32][65];
    __shared__ float ks[32][65];
    __shared__ float vs[32][65];
    __shared__ float at[32][33];
    __shared__ float raw[32][102];   // 10x10 halo tile per channel (stride 10)
    __shared__ float wsm[32][9];
    const int win = blockIdx.x;           // 0..575
    const int hd = blockIdx.y;            // 0..5
    const int h1 = win / 24, w1 = win - h1 * 24;
    const int tid = threadIdx.x;
    const int gy0 = h1 * 8 - 1, gx0 = w1 * 8 - 1;
    const size_t base_hw = (size_t)(h1 * 8) * L + w1 * 8;

    for (int z = 0; z < 3; ++z) {
        float(*dst)[65] = (z == 0) ? qs : (z == 1) ? ks : vs;
        size_t cbase = ((size_t)z * Cc + hd * 32) * S;
#pragma unroll
        for (int i = 0; i < 2; ++i) {
            int idx = i * BLK + tid;
            if (idx < 288) {
                int c = idx / 9, k = idx - c * 9;
                wsm[c][k] = w_dw[((size_t)z * Cc + hd * 32 + c) * 9 + k];
            }
        }
#pragma unroll
        for (int i = 0; i < 13; ++i) {
            int idx = i * BLK + tid;
            if (idx < 3200) {
                int c = idx / 100, pp = idx - c * 100;
                int iy = pp / 10, ix = pp - iy * 10;
                int gy = gy0 + iy, gx = gx0 + ix;
                float v = 0.f;
                if (gy >= 0 && gy < L && gx >= 0 && gx < L)
                    v = __bfloat162float(qkv[cbase + (size_t)c * S + (size_t)gy * L + gx]);
                raw[c][pp] = v;
            }
        }
        __syncthreads();
#pragma unroll
        for (int i = 0; i < 8; ++i) {
            int idx = i * BLK + tid;
            int c = idx >> 6, e = idx & 63;
            int ii = e >> 3, jj = e & 7;
            float acc = 0.f;
#pragma unroll
            for (int t = 0; t < 9; ++t) {
                int dy = t / 3, dx = t - dy * 3;
                acc += wsm[c][t] * raw[c][(ii + dy) * 10 + (jj + dx)];
            }
            dst[c][e] = acc;
        }
        __syncthreads();
    }

    const int r = tid >> 3, u = tid & 7;  // 32 rows x 8 lanes
    {
        float sq = 0.f, sk = 0.f;
#pragma unroll
        for (int j = 0; j < 8; ++j) {
            float a = qs[r][u + 8 * j]; sq += a * a;
            float c2 = ks[r][u + 8 * j]; sk += c2 * c2;
        }
#pragma unroll
        for (int m = 1; m < 8; m <<= 1) {
            sq += __shfl_xor(sq, m, 8);
            sk += __shfl_xor(sk, m, 8);
        }
        float fq = 1.f / fmaxf(sqrtf(sq), 1e-12f);
        float fk = 1.f / fmaxf(sqrtf(sk), 1e-12f);
#pragma unroll
        for (int j = 0; j < 8; ++j) {
            qs[r][u + 8 * j] *= fq;
            ks[r][u + 8 * j] *= fk;
        }
    }
    __syncthreads();
    {
        const int c = tid >> 3, dg = tid & 7;
        float a0 = 0.f, a1 = 0.f, a2 = 0.f, a3 = 0.f;
        for (int e = 0; e < 64; ++e) {
            float qv = qs[c][e];
            a0 += qv * ks[dg * 4 + 0][e];
            a1 += qv * ks[dg * 4 + 1][e];
            a2 += qv * ks[dg * 4 + 2][e];
            a3 += qv * ks[dg * 4 + 3][e];
        }
        float t = temp[hd];
        at[c][dg * 4 + 0] = a0 * t;
        at[c][dg * 4 + 1] = a1 * t;
        at[c][dg * 4 + 2] = a2 * t;
        at[c][dg * 4 + 3] = a3 * t;
    }
    __syncthreads();
    {
        float mx = -1e30f;
#pragma unroll
        for (int j = 0; j < 4; ++j) mx = fmaxf(mx, at[r][u + 8 * j]);
#pragma unroll
        for (int m = 1; m < 8; m <<= 1) mx = fmaxf(mx, __shfl_xor(mx, m, 8));
        float pv[4], sm = 0.f;
#pragma unroll
        for (int j = 0; j < 4; ++j) {
            pv[j] = __expf(at[r][u + 8 * j] - mx);
            sm += pv[j];
        }
#pragma unroll
        for (int m = 1; m < 8; m <<= 1) sm += __shfl_xor(sm, m, 8);
        float inv = 1.f / sm;
#pragma unroll
        for (int j = 0; j < 4; ++j) at[r][u + 8 * j] = pv[j] * inv;
    }
    __syncthreads();
    {
        const int c = tid >> 3;
        float o[8];
#pragma unroll
        for (int j = 0; j < 8; ++j) o[j] = 0.f;
        for (int d = 0; d < 32; ++d) {
            float a = at[c][d];
#pragma unroll
            for (int j = 0; j < 8; ++j) o[j] += a * vs[d][u + 8 * j];
        }
        size_t obase = ((size_t)(hd * 32 + c)) * S + base_hw;
#pragma unroll
        for (int j = 0; j < 8; ++j)
            stf(outp + obase + (size_t)j * L + u, o[j]);
    }
}

// ---------------- FFN strip GEMM: f_strip[m][h][wl], wl in [0,PW) ------------
__global__ __launch_bounds__(BLK) void k_fstrip(const float* __restrict__ Wm,
                                                const bft* __restrict__ In,
                                                bft* __restrict__ Out, int w0) {
    __shared__ float As[16][68];
    __shared__ float Bs[16][68];
    const int M = 2 * HID, K = Cc, NS = L * PW;   // 1020, 192, 9600
    const int tid = threadIdx.x;
    const int tx = tid & 15, ty = tid >> 4;
    const int n0 = blockIdx.x * 64, m0 = blockIdx.y * 64;
    float acc[4][4] = {{0.f}};
    for (int k0 = 0; k0 < K; k0 += 16) {
#pragma unroll
        for (int i = 0; i < 4; ++i) {
            int idx = i * BLK + tid;
            int kk = idx & 15, m = idx >> 4;
            int gm = m0 + m;
            float v = 0.f;
            if (gm < M) v = Wm[(size_t)gm * K + k0 + kk];
            As[kk][m] = v;
        }
#pragma unroll
        for (int i = 0; i < 4; ++i) {
            int idx = i * BLK + tid;
            int n = idx & 63, kk = idx >> 6;
            int gn = n0 + n;
            int h = gn / PW, wl = gn - h * PW;
            int wg = w0 - 1 + wl;
            float v = 0.f;
            if (wg >= 0 && wg < L)
                v = ldf(In + (size_t)(k0 + kk) * S + (size_t)h * L + wg);
            Bs[kk][n] = v;
        }
        __syncthreads();
#pragma unroll
        for (int kk = 0; kk < 16; ++kk) {
            float a[4], bv[4];
#pragma unroll
            for (int i = 0; i < 4; ++i) a[i] = As[kk][ty * 4 + i];
#pragma unroll
            for (int j = 0; j < 4; ++j) bv[j] = Bs[kk][tx * 4 + j];
#pragma unroll
            for (int i = 0; i < 4; ++i)
#pragma unroll
                for (int j = 0; j < 4; ++j) acc[i][j] += a[i] * bv[j];
        }
        __syncthreads();
    }
#pragma unroll
    for (int i = 0; i < 4; ++i) {
        int m = m0 + ty * 4 + i;
        if (m >= M) continue;
#pragma unroll
        for (int j = 0; j < 4; ++j) {
            int n = n0 + tx * 4 + j;
            stf(Out + (size_t)m * NS + n, acc[i][j]);
        }
    }
}

// ---------------- FFN gate on strip: g[c][h][wl], wl in [0,SW) ---------------
__global__ __launch_bounds__(BLK) void k_gate(const bft* __restrict__ f,
                                              const float* __restrict__ wt,
                                              bft* __restrict__ g) {
    const int NS = L * PW, NG = L * SW;  // 9600, 9216
    int idx = blockIdx.x * BLK + threadIdx.x;   // < 510*9216
    int c = idx / NG, pp = idx - c * NG;
    int h = pp / SW, wl = pp - h * SW;
    const bft* f1 = f + (size_t)c * NS;
    const bft* f2 = f + (size_t)(c + HID) * NS;
    float a1 = 0.f, a2 = 0.f;
#pragma unroll
    for (int dy = 0; dy < 3; ++dy) {
        int hh = h + dy - 1;
        if (hh < 0 || hh >= L) continue;
#pragma unroll
        for (int dx = 0; dx < 3; ++dx) {
            int ww = wl + dx;  // 0..49, always inside strip
            float w1 = wt[(size_t)c * 9 + dy * 3 + dx];
            float w2 = wt[((size_t)c + HID) * 9 + dy * 3 + dx];
            a1 += w1 * __bfloat162float(f1[(size_t)hh * PW + ww]);
            a2 += w2 * __bfloat162float(f2[(size_t)hh * PW + ww]);
        }
    }
    float ge = 0.5f * a1 * (1.f + erff(a1 * 0.70710678118654752f));
    g[idx] = __float2bfloat16(ge * a2);
}

// ---------------- w_out GEMM on strip + x1 residual -> d_out (fp32) ----------
__global__ __launch_bounds__(BLK) void k_wout(const float* __restrict__ Wm,
                                              const bft* __restrict__ g,
                                              const bft* __restrict__ x1,
                                              float* __restrict__ Out, int w0) {
    __shared__ float As[16][68];
    __shared__ float Bs[16][68];
    const int M = Cc, K = HID, NG = L * SW;   // 192, 510, 9216
    const int tid = threadIdx.x;
    const int tx = tid & 15, ty = tid >> 4;
    const int n0 = blockIdx.x * 64, m0 = blockIdx.y * 64;
    float acc[4][4] = {{0.f}};
    for (int k0 = 0; k0 < K; k0 += 16) {
#pragma unroll
        for (int i = 0; i < 4; ++i) {
            int idx = i * BLK + tid;
            int kk = idx & 15, m = idx >> 4;
            int gk = k0 + kk;
            float v = 0.f;
            if (gk < K) v = Wm[(size_t)(m0 + m) * K + gk];
            As[kk][m] = v;
        }
#pragma unroll
        for (int i = 0; i < 4; ++i) {
            int idx = i * BLK + tid;
            int n = idx & 63, kk = idx >> 6;
            int gk = k0 + kk;
            float v = 0.f;
            if (gk < K) v = __bfloat162float(g[(size_t)gk * NG + n0 + n]);
            Bs[kk][n] = v;
        }
        __syncthreads();
#pragma unroll
        for (int kk = 0; kk < 16; ++kk) {
            float a[4], bv[4];
#pragma unroll
            for (int i = 0; i < 4; ++i) a[i] = As[kk][ty * 4 + i];
#pragma unroll
            for (int j = 0; j < 4; ++j) bv[j] = Bs[kk][tx * 4 + j];
#pragma unroll
            for (int i = 0; i < 4; ++i)
#pragma unroll
                for (int j = 0; j < 4; ++j) acc[i][j] += a[i] * bv[j];
        }
        __syncthreads();
    }
#pragma unroll
    for (int i = 0; i < 4; ++i) {
        int m = m0 + ty * 4 + i;
#pragma unroll
        for (int j = 0; j < 4; ++j) {
            int n = n0 + tx * 4 + j;
            int h = n / SW, wl = n - h * SW;
            size_t pix = (size_t)m * S + (size_t)h * L + w0 + wl;
            Out[pix] = acc[i][j] + __bfloat162float(x1[pix]);
        }
    }
}

// -----------------------------------------------------------------------------
extern "C" void kernel_launch(void* const* d_in, const int* in_sizes, int n_in,
                              void* d_out, int out_size, void* d_ws, size_t ws_size,
                              hipStream_t stream) {
    const float* x      = (const float*)d_in[0];
    const float* n1w    = (const float*)d_in[1];
    const float* n1b    = (const float*)d_in[2];
    const float* w_qkv  = (const float*)d_in[3];
    const float* w_dw   = (const float*)d_in[4];
    const float* temp   = (const float*)d_in[5];
    const float* w_proj = (const float*)d_in[6];
    const float* b_proj = (const float*)d_in[7];
    const float* n2w    = (const float*)d_in[8];
    const float* n2b    = (const float*)d_in[9];
    const float* w_in   = (const float*)d_in[10];
    const float* w_dwf  = (const float*)d_in[11];
    const float* w_out  = (const float*)d_in[12];
    float* outp = (float*)d_out;

    // workspace layout (99,237,888 bytes total)
    const size_t DCT_B = 147456;                       // fp32 192x192
    const size_t CS    = (size_t)Cc * S;               // one batch, 192 ch
    const size_t X1_B  = (size_t)Bn * CS * 2;          // 28,311,552
    const size_t P_B   = CS * 2;                       // 14,155,776
    const size_t NEED  = DCT_B + X1_B + 2 * P_B + (size_t)3 * CS * 2;
    if (ws_size < NEED) return;                        // clean fail, no OOB

    char* p = (char*)d_ws;
    float* dct = (float*)p;                p += DCT_B;
    bft* X1    = (bft*)p;                  p += X1_B;
    bft* Pb    = (bft*)p;                  p += P_B;
    bft* Qb    = (bft*)p;                  p += P_B;
    bft* QKV   = (bft*)p;                  // 42,467,328 B (also f_strip region)
    bft* fstrip = QKV;                     // 19,584,000 B used
    bft* gstrip = Qb;                      // 9,400,320 B used

    k_dct_init<<<144, BLK, 0, stream>>>(dct);

    for (int b = 0; b < Bn; ++b) {
        const float* xb = x + (size_t)b * CS;
        bft* x1b = X1 + (size_t)b * CS;
        // attention branch
        k_ln<float><<<S / BLK, BLK, 0, stream>>>(xb, n1w, n1b, Pb);
        k_transform<0, false><<<dim3(3, 3, Cc), BLK, 0, stream>>>(dct, Pb, Qb, nullptr);
        k_transform<1, false><<<dim3(3, 3, Cc), BLK, 0, stream>>>(dct, Qb, Pb, nullptr);
        k_conv1x1<false><<<dim3(576, 9), BLK, 0, stream>>>(w_qkv, Pb, QKV, nullptr, 576, 192);
        k_attn<<<dim3(576, 6), BLK, 0, stream>>>(QKV, w_dw, temp, Qb);
        k_conv1x1<true><<<dim3(576, 3), BLK, 0, stream>>>(w_proj, Qb, Pb, b_proj, 192, 192);
        k_transform<2, false><<<dim3(3, 3, Cc), BLK, 0, stream>>>(dct, Pb, Qb, nullptr);
        k_transform<3, true><<<dim3(3, 3, Cc), BLK, 0, stream>>>(dct, Qb, x1b, xb);
    }
    for (int b = 0; b < Bn; ++b) {
        bft* x1b = X1 + (size_t)b * CS;
        float* outb = outp + (size_t)b * CS;
        // FFN branch: z in Pb, then 4 column strips of 48
        k_ln<bft><<<S / BLK, BLK, 0, stream>>>(x1b, n2w, n2b, Pb);
        for (int st = 0; st < 4; ++st) {
            int w0 = st * SW;
            k_fstrip<<<dim3(150, 16), BLK, 0, stream>>>(w_in, Pb, fstrip, w0);
            k_gate<<<(HID * L * SW) / BLK, BLK, 0, stream>>>(fstrip, w_dwf, gstrip);
            k_wout<<<dim3(144, 3), BLK, 0, stream>>>(w_out, gstrip, x1b, outb, w0);
        }
    }
}

// Round 5
// 1941.625 us; speedup vs baseline: 1.2274x; 1.2274x over previous
//
#include <hip/hip_runtime.h>
#include <hip/hip_bf16.h>

typedef __hip_bfloat16 bft;
typedef __attribute__((ext_vector_type(8))) short bf16x8;
typedef __attribute__((ext_vector_type(4))) float f32x4;

#define BLK 256
static constexpr int Cc = 192;     // channels
static constexpr int L  = 192;     // H = W
static constexpr int S  = 36864;   // L*L
static constexpr int Bn = 2;       // batch
static constexpr int HID = 510;    // int(192*2.66)
static constexpr int PW = 50;      // FFN strip width incl. halo
static constexpr int SW = 48;      // FFN strip output width
static constexpr double PI_D = 3.141592653589793238462643383279502884;

__device__ __forceinline__ float ldf(const float* p) { return *p; }
__device__ __forceinline__ float ldf(const bft* p)   { return __bfloat162float(*p); }
__device__ __forceinline__ void  stf(float* p, float v) { *p = v; }
__device__ __forceinline__ void  stf(bft* p, float v)   { *p = __float2bfloat16(v); }
__device__ __forceinline__ unsigned short f2bfu(float f) {
    bft h = __float2bfloat16(f);
    return *reinterpret_cast<const unsigned short*>(&h);
}
__device__ __forceinline__ unsigned short bfu(const bft* p) {
    return *reinterpret_cast<const unsigned short*>(p);
}

// ---------------- DCT matrix init (orthonormal DCT-II, fp32) -----------------
__global__ __launch_bounds__(BLK) void k_dct_init(float* __restrict__ dct) {
    int idx = blockIdx.x * BLK + threadIdx.x;
    if (idx >= L * L) return;
    int p = idx / L, h = idx - p * L;
    double v = (p == 0) ? sqrt(1.0 / L)
                        : cos(PI_D * p * (2 * h + 1) / (2.0 * L)) * sqrt(2.0 / L);
    dct[idx] = (float)v;
}

// ---------------- LayerNorm over channel dim (per batch) ---------------------
template <typename TI>
__global__ __launch_bounds__(BLK) void k_ln(const TI* __restrict__ x,
                                            const float* __restrict__ w,
                                            const float* __restrict__ b,
                                            bft* __restrict__ out) {
    int s = blockIdx.x * BLK + threadIdx.x;   // [0, S)
    const TI* xp = x + s;
    float sum = 0.f, sq = 0.f;
    for (int c = 0; c < Cc; ++c) {
        float v = ldf(xp + (size_t)c * S);
        sum += v; sq += v * v;
    }
    float mu = sum * (1.f / Cc);
    float var = sq * (1.f / Cc) - mu * mu;
    float r = rsqrtf(var + 1e-5f);
    for (int c = 0; c < Cc; ++c) {
        float v = ldf(xp + (size_t)c * S);
        stf(out + s + (size_t)c * S, (v - mu) * r * w[c] + b[c]);
    }
}

// =============================================================================
// Generic MFMA bf16 GEMM: Out[m][n] = sum_k A[m][k] * B[k][n]  (+bias, +resid)
// Tile 64x64, BK=32, 4 waves (2x2), each wave 32x32 via 2x2 16x16x32 MFMA.
// AMODE: 0 = bf16 [m][k] (strideA, zA batch)           (activations)
//        1 = fp32 [m][k] w/ Mreal/Kreal zero-pad       (weights, dct)
//        2 = fp32 [k][m] transposed read               (dct^T)
// BMODE: 0 = bf16 [k][n] (strideB, zB batch)
//        1 = bf16 strip gather from [k][S]: n->(h,wl), wg=w0-1+wl, 0-pad OOB
//        2 = fp32 [n][k] (k-contig; dct^T as B)
//        3 = fp32 [k][n]                                (dct as B)
// OMODE: 0 = linear idx = bz*zO + m*strideO + n
//        1 = strip: h=n/SW, wl=n%SW, idx = m*S + h*L + w0+wl
// =============================================================================
template <int AMODE, int BMODE, int OMODE, bool HASBIAS, bool HASRES,
          typename OutT, typename ResT>
__global__ __launch_bounds__(BLK) void k_gemm(
    const void* __restrict__ Ap, int strideA, int Mreal, int Kreal, long zA,
    const void* __restrict__ Bp, int strideB, long zB,
    OutT* __restrict__ Out, int strideO, long zO,
    const float* __restrict__ bias,
    const ResT* __restrict__ Res, long zR,
    int K, int w0) {
    __shared__ unsigned short Al[64][40];
    __shared__ unsigned short Bl[64][40];
    const int tid = threadIdx.x;
    const int n0 = blockIdx.x * 64, m0 = blockIdx.y * 64, bz = blockIdx.z;
    const int lane = tid & 63, wv = tid >> 6;
    const int wr = wv >> 1, wc = wv & 1;
    const int l15 = lane & 15, l4 = lane >> 4;
    f32x4 acc[2][2] = {};
    const int am = tid >> 2, ak = (tid & 3) * 8;   // A staging: 8 k-contig / thr
    const int bn = tid & 63, bk = (tid >> 6) * 8;  // B staging: 8 k / thr at col bn
    // strip-mode B precompute
    int b_h = 0, b_wg = 0; bool b_ok = true;
    if constexpr (BMODE == 1) {
        int gn = n0 + bn; b_h = gn / PW; int wl = gn - b_h * PW; b_wg = w0 - 1 + wl;
        b_ok = (b_wg >= 0 && b_wg < L);
    }
    for (int k0 = 0; k0 < K; k0 += 32) {
        // ---- stage A tile -> Al[am][ak..ak+7]
        {
            unsigned short v[8];
            if constexpr (AMODE == 0) {
                const bft* A = (const bft*)Ap + (size_t)bz * zA
                             + (size_t)(m0 + am) * strideA + k0 + ak;
                *reinterpret_cast<uint4*>(v) = *reinterpret_cast<const uint4*>(A);
            } else if constexpr (AMODE == 1) {
                const float* A = (const float*)Ap + (size_t)bz * zA;
                int gm = m0 + am;
#pragma unroll
                for (int e = 0; e < 8; ++e) {
                    int gk = k0 + ak + e;
                    float f = (gm < Mreal && gk < Kreal)
                                  ? A[(size_t)gm * strideA + gk] : 0.f;
                    v[e] = f2bfu(f);
                }
            } else {  // AMODE 2: A[m][k] = src[k][m]
                const float* A = (const float*)Ap;
#pragma unroll
                for (int e = 0; e < 8; ++e)
                    v[e] = f2bfu(A[(size_t)(k0 + ak + e) * strideA + (m0 + am)]);
            }
            *reinterpret_cast<uint4*>(&Al[am][ak]) = *reinterpret_cast<uint4*>(v);
        }
        // ---- stage B tile (transposed) -> Bl[bn][bk..bk+7]
        {
            unsigned short v[8];
            if constexpr (BMODE == 0) {
                const bft* B = (const bft*)Bp + (size_t)bz * zB
                             + (size_t)(k0 + bk) * strideB + n0 + bn;
#pragma unroll
                for (int e = 0; e < 8; ++e) v[e] = bfu(B + (size_t)e * strideB);
            } else if constexpr (BMODE == 1) {
                const bft* B = (const bft*)Bp + (size_t)(k0 + bk) * S
                             + (size_t)b_h * L + b_wg;
#pragma unroll
                for (int e = 0; e < 8; ++e)
                    v[e] = b_ok ? bfu(B + (size_t)e * S) : (unsigned short)0;
            } else if constexpr (BMODE == 2) {  // fp32 [n][k]
                const float* B = (const float*)Bp + (size_t)(n0 + bn) * strideB + k0 + bk;
#pragma unroll
                for (int e = 0; e < 8; ++e) v[e] = f2bfu(B[e]);
            } else {  // BMODE 3: fp32 [k][n]
                const float* B = (const float*)Bp + (size_t)(k0 + bk) * strideB + n0 + bn;
#pragma unroll
                for (int e = 0; e < 8; ++e) v[e] = f2bfu(B[(size_t)e * strideB]);
            }
            *reinterpret_cast<uint4*>(&Bl[bn][bk]) = *reinterpret_cast<uint4*>(v);
        }
        __syncthreads();
        bf16x8 af[2], bf[2];
#pragma unroll
        for (int i = 0; i < 2; ++i) {
            af[i] = *reinterpret_cast<const bf16x8*>(&Al[wr * 32 + i * 16 + l15][l4 * 8]);
            bf[i] = *reinterpret_cast<const bf16x8*>(&Bl[wc * 32 + i * 16 + l15][l4 * 8]);
        }
#pragma unroll
        for (int i = 0; i < 2; ++i)
#pragma unroll
            for (int j = 0; j < 2; ++j)
                acc[i][j] = __builtin_amdgcn_mfma_f32_16x16x32_bf16(
                    af[i], bf[j], acc[i][j], 0, 0, 0);
        __syncthreads();
    }
    // ---- epilogue: D row = (lane>>4)*4+reg, col = lane&15
#pragma unroll
    for (int i = 0; i < 2; ++i) {
        int mBase = m0 + wr * 32 + i * 16 + l4 * 4;
#pragma unroll
        for (int j = 0; j < 2; ++j) {
            int n = n0 + wc * 32 + j * 16 + l15;
#pragma unroll
            for (int r = 0; r < 4; ++r) {
                int m = mBase + r;
                float vv = acc[i][j][r];
                if constexpr (HASBIAS) vv += bias[m];
                size_t idx;
                if constexpr (OMODE == 0)
                    idx = (size_t)bz * zO + (size_t)m * strideO + n;
                else {
                    int h = n / SW, wl = n - h * SW;
                    idx = (size_t)m * S + (size_t)h * L + w0 + wl;
                }
                if constexpr (HASRES) vv += ldf(Res + ((OMODE == 0)
                                  ? ((size_t)bz * zR + (size_t)m * strideO + n) : idx));
                stf(Out + idx, vv);
            }
        }
    }
}

// ---------------- window channel attention with fused depthwise 3x3 ----------
__global__ __launch_bounds__(BLK) void k_attn(const bft* __restrict__ qkv,
                                              const float* __restrict__ w_dw,
                                              const float* __restrict__ temp,
                                              bft* __restrict__ outp) {
    __shared__ float qs[32][65];
    __shared__ float ks[32][65];
    __shared__ float vs[32][65];
    __shared__ float at[32][33];
    __shared__ float raw[32][102];
    __shared__ float wsm[32][9];
    const int win = blockIdx.x;
    const int hd = blockIdx.y;
    const int h1 = win / 24, w1 = win - h1 * 24;
    const int tid = threadIdx.x;
    const int gy0 = h1 * 8 - 1, gx0 = w1 * 8 - 1;
    const size_t base_hw = (size_t)(h1 * 8) * L + w1 * 8;

    for (int z = 0; z < 3; ++z) {
        float(*dst)[65] = (z == 0) ? qs : (z == 1) ? ks : vs;
        size_t cbase = ((size_t)z * Cc + hd * 32) * S;
#pragma unroll
        for (int i = 0; i < 2; ++i) {
            int idx = i * BLK + tid;
            if (idx < 288) {
                int c = idx / 9, k = idx - c * 9;
                wsm[c][k] = w_dw[((size_t)z * Cc + hd * 32 + c) * 9 + k];
            }
        }
#pragma unroll
        for (int i = 0; i < 13; ++i) {
            int idx = i * BLK + tid;
            if (idx < 3200) {
                int c = idx / 100, pp = idx - c * 100;
                int iy = pp / 10, ix = pp - iy * 10;
                int gy = gy0 + iy, gx = gx0 + ix;
                float v = 0.f;
                if (gy >= 0 && gy < L && gx >= 0 && gx < L)
                    v = __bfloat162float(qkv[cbase + (size_t)c * S + (size_t)gy * L + gx]);
                raw[c][pp] = v;
            }
        }
        __syncthreads();
#pragma unroll
        for (int i = 0; i < 8; ++i) {
            int idx = i * BLK + tid;
            int c = idx >> 6, e = idx & 63;
            int ii = e >> 3, jj = e & 7;
            float acc = 0.f;
#pragma unroll
            for (int t = 0; t < 9; ++t) {
                int dy = t / 3, dx = t - dy * 3;
                acc += wsm[c][t] * raw[c][(ii + dy) * 10 + (jj + dx)];
            }
            dst[c][e] = acc;
        }
        __syncthreads();
    }

    const int r = tid >> 3, u = tid & 7;
    {
        float sq = 0.f, sk = 0.f;
#pragma unroll
        for (int j = 0; j < 8; ++j) {
            float a = qs[r][u + 8 * j]; sq += a * a;
            float c2 = ks[r][u + 8 * j]; sk += c2 * c2;
        }
#pragma unroll
        for (int m = 1; m < 8; m <<= 1) {
            sq += __shfl_xor(sq, m, 8);
            sk += __shfl_xor(sk, m, 8);
        }
        float fq = 1.f / fmaxf(sqrtf(sq), 1e-12f);
        float fk = 1.f / fmaxf(sqrtf(sk), 1e-12f);
#pragma unroll
        for (int j = 0; j < 8; ++j) {
            qs[r][u + 8 * j] *= fq;
            ks[r][u + 8 * j] *= fk;
        }
    }
    __syncthreads();
    {
        const int c = tid >> 3, dg = tid & 7;
        float a0 = 0.f, a1 = 0.f, a2 = 0.f, a3 = 0.f;
        for (int e = 0; e < 64; ++e) {
            float qv = qs[c][e];
            a0 += qv * ks[dg * 4 + 0][e];
            a1 += qv * ks[dg * 4 + 1][e];
            a2 += qv * ks[dg * 4 + 2][e];
            a3 += qv * ks[dg * 4 + 3][e];
        }
        float t = temp[hd];
        at[c][dg * 4 + 0] = a0 * t;
        at[c][dg * 4 + 1] = a1 * t;
        at[c][dg * 4 + 2] = a2 * t;
        at[c][dg * 4 + 3] = a3 * t;
    }
    __syncthreads();
    {
        float mx = -1e30f;
#pragma unroll
        for (int j = 0; j < 4; ++j) mx = fmaxf(mx, at[r][u + 8 * j]);
#pragma unroll
        for (int m = 1; m < 8; m <<= 1) mx = fmaxf(mx, __shfl_xor(mx, m, 8));
        float pv[4], sm = 0.f;
#pragma unroll
        for (int j = 0; j < 4; ++j) {
            pv[j] = __expf(at[r][u + 8 * j] - mx);
            sm += pv[j];
        }
#pragma unroll
        for (int m = 1; m < 8; m <<= 1) sm += __shfl_xor(sm, m, 8);
        float inv = 1.f / sm;
#pragma unroll
        for (int j = 0; j < 4; ++j) at[r][u + 8 * j] = pv[j] * inv;
    }
    __syncthreads();
    {
        const int c = tid >> 3;
        float o[8];
#pragma unroll
        for (int j = 0; j < 8; ++j) o[j] = 0.f;
        for (int d = 0; d < 32; ++d) {
            float a = at[c][d];
#pragma unroll
            for (int j = 0; j < 8; ++j) o[j] += a * vs[d][u + 8 * j];
        }
        size_t obase = ((size_t)(hd * 32 + c)) * S + base_hw;
#pragma unroll
        for (int j = 0; j < 8; ++j)
            stf(outp + obase + (size_t)j * L + u, o[j]);
    }
}

// ---------------- FFN gate on strip: g[c][h][wl], wl in [0,SW) ---------------
__global__ __launch_bounds__(BLK) void k_gate(const bft* __restrict__ f,
                                              const float* __restrict__ wt,
                                              bft* __restrict__ g) {
    const int NS = L * PW, NG = L * SW;  // 9600, 9216
    int idx = blockIdx.x * BLK + threadIdx.x;   // < 510*9216
    int c = idx / NG, pp = idx - c * NG;
    int h = pp / SW, wl = pp - h * SW;
    const bft* f1 = f + (size_t)c * NS;
    const bft* f2 = f + (size_t)(c + HID) * NS;
    float a1 = 0.f, a2 = 0.f;
#pragma unroll
    for (int dy = 0; dy < 3; ++dy) {
        int hh = h + dy - 1;
        if (hh < 0 || hh >= L) continue;
#pragma unroll
        for (int dx = 0; dx < 3; ++dx) {
            int ww = wl + dx;
            float w1 = wt[(size_t)c * 9 + dy * 3 + dx];
            float w2 = wt[((size_t)c + HID) * 9 + dy * 3 + dx];
            a1 += w1 * __bfloat162float(f1[(size_t)hh * PW + ww]);
            a2 += w2 * __bfloat162float(f2[(size_t)hh * PW + ww]);
        }
    }
    float ge = 0.5f * a1 * (1.f + erff(a1 * 0.70710678118654752f));
    g[idx] = __float2bfloat16(ge * a2);
}

// -----------------------------------------------------------------------------
extern "C" void kernel_launch(void* const* d_in, const int* in_sizes, int n_in,
                              void* d_out, int out_size, void* d_ws, size_t ws_size,
                              hipStream_t stream) {
    const float* x      = (const float*)d_in[0];
    const float* n1w    = (const float*)d_in[1];
    const float* n1b    = (const float*)d_in[2];
    const float* w_qkv  = (const float*)d_in[3];
    const float* w_dw   = (const float*)d_in[4];
    const float* temp   = (const float*)d_in[5];
    const float* w_proj = (const float*)d_in[6];
    const float* b_proj = (const float*)d_in[7];
    const float* n2w    = (const float*)d_in[8];
    const float* n2b    = (const float*)d_in[9];
    const float* w_in   = (const float*)d_in[10];
    const float* w_dwf  = (const float*)d_in[11];
    const float* w_out  = (const float*)d_in[12];
    float* outp = (float*)d_out;

    // workspace layout (99,237,888 bytes total — same as known-good round 4)
    const size_t DCT_B = 147456;                       // fp32 192x192
    const size_t CS    = (size_t)Cc * S;               // one batch, 192 ch
    const size_t X1_B  = (size_t)Bn * CS * 2;
    const size_t P_B   = CS * 2;
    const size_t NEED  = DCT_B + X1_B + 2 * P_B + (size_t)3 * CS * 2;
    if (ws_size < NEED) return;

    char* p = (char*)d_ws;
    float* dct = (float*)p;                p += DCT_B;
    bft* X1    = (bft*)p;                  p += X1_B;
    bft* Pb    = (bft*)p;                  p += P_B;
    bft* Qb    = (bft*)p;                  p += P_B;
    bft* QKV   = (bft*)p;                  // 42,467,328 B (also f region in FFN)
    bft* fbuf  = QKV;                      // 1024 x 9600 bf16 = 19,660,800 B
    bft* gstrip = Qb;                      // 512 x 9216 bf16 = 9,437,184 B (Qb free in FFN)

    k_dct_init<<<144, BLK, 0, stream>>>(dct);

    for (int b = 0; b < Bn; ++b) {
        const float* xb = x + (size_t)b * CS;
        bft* x1b = X1 + (size_t)b * CS;
        // LN1
        k_ln<float><<<S / BLK, BLK, 0, stream>>>(xb, n1w, n1b, Pb);
        // t = Mh @ Y  (batched over c):  A=dct fp32 [192][192], B=Pb_c bf16 [h][w]
        k_gemm<1, 0, 0, false, false, bft, float><<<dim3(3, 3, Cc), BLK, 0, stream>>>(
            dct, L, L, L, 0,  Pb, L, S,  Qb, L, S,  nullptr, nullptr, 0,  L, 0);
        // yd = T @ Mw^T (flattened):    A=Qb bf16 [36864][192], B=dct^T (fp32 [n][k])
        k_gemm<0, 2, 0, false, false, bft, float><<<dim3(3, 576, 1), BLK, 0, stream>>>(
            Qb, L, 0, 0, 0,  dct, L, 0,  Pb, L, 0,  nullptr, nullptr, 0,  L, 0);
        // qkv = W_qkv @ yd:  A=w_qkv fp32 [576][192], B=Pb bf16 [192][36864]
        k_gemm<1, 0, 0, false, false, bft, float><<<dim3(576, 9, 1), BLK, 0, stream>>>(
            w_qkv, Cc, 576, Cc, 0,  Pb, S, 0,  QKV, S, 0,  nullptr, nullptr, 0,  Cc, 0);
        // attention (fused dwconv)
        k_attn<<<dim3(576, 6), BLK, 0, stream>>>(QKV, w_dw, temp, Qb);
        // proj + bias
        k_gemm<1, 0, 0, true, false, bft, float><<<dim3(576, 3, 1), BLK, 0, stream>>>(
            w_proj, Cc, Cc, Cc, 0,  Qb, S, 0,  Pb, S, 0,  b_proj, nullptr, 0,  Cc, 0);
        // u = P @ Mw (flattened):  A=Pb bf16 [36864][192], B=dct fp32 [k][n]
        k_gemm<0, 3, 0, false, false, bft, float><<<dim3(3, 576, 1), BLK, 0, stream>>>(
            Pb, L, 0, 0, 0,  dct, L, 0,  Qb, L, 0,  nullptr, nullptr, 0,  L, 0);
        // x1 = Mh^T @ U + x (batched over c):  A=dct^T (fp32 transposed read)
        k_gemm<2, 0, 0, false, true, bft, float><<<dim3(3, 3, Cc), BLK, 0, stream>>>(
            dct, L, 0, 0, 0,  Qb, L, S,  x1b, L, S,  nullptr, xb, S,  L, 0);
    }
    for (int b = 0; b < Bn; ++b) {
        bft* x1b = X1 + (size_t)b * CS;
        float* outb = outp + (size_t)b * CS;
        // LN2
        k_ln<bft><<<S / BLK, BLK, 0, stream>>>(x1b, n2w, n2b, Pb);
        for (int st = 0; st < 4; ++st) {
            int w0 = st * SW;
            // f = W_in @ z (strip, halo): A=w_in fp32 [1020->1024][192], B strip gather
            k_gemm<1, 1, 0, false, false, bft, float><<<dim3(150, 16, 1), BLK, 0, stream>>>(
                w_in, Cc, 2 * HID, Cc, 0,  Pb, S, 0,  fbuf, L * PW, 0,
                nullptr, nullptr, 0,  Cc, w0);
            // gated dwconv + GELU
            k_gate<<<(HID * L * SW) / BLK, BLK, 0, stream>>>(fbuf, w_dwf, gstrip);
            // out = W_out @ g + x1 (strip out): A=w_out fp32 [192][510->512]
            k_gemm<1, 0, 1, false, true, float, bft><<<dim3(144, 3, 1), BLK, 0, stream>>>(
                w_out, HID, Cc, HID, 0,  gstrip, L * SW, 0,  outb, 0, 0,
                nullptr, x1b, 0,  512, w0);
        }
    }
}

// Round 6
// 1928.786 us; speedup vs baseline: 1.2356x; 1.0067x over previous
//
#include <hip/hip_runtime.h>
#include <hip/hip_bf16.h>

typedef __hip_bfloat16 bft;
typedef __attribute__((ext_vector_type(8))) short bf16x8;
typedef __attribute__((ext_vector_type(4))) float f32x4;

#define BLK 256
static constexpr int Cc = 192;     // channels
static constexpr int L  = 192;     // H = W
static constexpr int S  = 36864;   // L*L
static constexpr int Bn = 2;       // batch
static constexpr int HID = 510;    // int(192*2.66)
static constexpr int PW = 50;      // FFN strip width incl. halo
static constexpr int SW = 48;      // FFN strip output width
static constexpr double PI_D = 3.141592653589793238462643383279502884;

__device__ __forceinline__ float ldf(const float* p) { return *p; }
__device__ __forceinline__ float ldf(const bft* p)   { return __bfloat162float(*p); }
__device__ __forceinline__ void  stf(float* p, float v) { *p = v; }
__device__ __forceinline__ void  stf(bft* p, float v)   { *p = __float2bfloat16(v); }
__device__ __forceinline__ unsigned short f2bfu(float f) {
    bft h = __float2bfloat16(f);
    return *reinterpret_cast<const unsigned short*>(&h);
}
__device__ __forceinline__ unsigned short bfu(const bft* p) {
    return *reinterpret_cast<const unsigned short*>(p);
}
__device__ __forceinline__ float bu2f(unsigned short u) {
    unsigned int x = (unsigned int)u << 16;
    return __uint_as_float(x);
}

// ---------------- DCT matrix init (orthonormal DCT-II, fp32) -----------------
__global__ __launch_bounds__(BLK) void k_dct_init(float* __restrict__ dct) {
    int idx = blockIdx.x * BLK + threadIdx.x;
    if (idx >= L * L) return;
    int p = idx / L, h = idx - p * L;
    double v = (p == 0) ? sqrt(1.0 / L)
                        : cos(PI_D * p * (2 * h + 1) / (2.0 * L)) * sqrt(2.0 / L);
    dct[idx] = (float)v;
}

// ---------------- LayerNorm over channel dim (per batch) ---------------------
template <typename TI>
__global__ __launch_bounds__(BLK) void k_ln(const TI* __restrict__ x,
                                            const float* __restrict__ w,
                                            const float* __restrict__ b,
                                            bft* __restrict__ out) {
    int s = blockIdx.x * BLK + threadIdx.x;   // [0, S)
    const TI* xp = x + s;
    float sum = 0.f, sq = 0.f;
    for (int c = 0; c < Cc; ++c) {
        float v = ldf(xp + (size_t)c * S);
        sum += v; sq += v * v;
    }
    float mu = sum * (1.f / Cc);
    float var = sq * (1.f / Cc) - mu * mu;
    float r = rsqrtf(var + 1e-5f);
    for (int c = 0; c < Cc; ++c) {
        float v = ldf(xp + (size_t)c * S);
        stf(out + s + (size_t)c * S, (v - mu) * r * w[c] + b[c]);
    }
}

// =============================================================================
// Generic MFMA bf16 GEMM: Out[m][n] = sum_k A[m][k] * B[k][n]  (+bias, +resid)
// Tile 64x64, BK=32, 4 waves (2x2), each wave 32x32 via 2x2 16x16x32 MFMA.
// AMODE: 0 = bf16 [m][k]; 1 = fp32 [m][k] w/ M/K zero-pad; 2 = fp32 [k][m]
// BMODE: 0 = bf16 [k][n]; 1 = strip gather from [k][S]; 2 = fp32 [n][k];
//        3 = fp32 [k][n]
// OMODE: 0 = linear; 1 = FFN strip; 2 = window-tiled col -> spatial decode
// =============================================================================
template <int AMODE, int BMODE, int OMODE, bool HASBIAS, bool HASRES,
          typename OutT, typename ResT>
__global__ __launch_bounds__(BLK) void k_gemm(
    const void* __restrict__ Ap, int strideA, int Mreal, int Kreal, long zA,
    const void* __restrict__ Bp, int strideB, long zB,
    OutT* __restrict__ Out, int strideO, long zO,
    const float* __restrict__ bias,
    const ResT* __restrict__ Res, long zR,
    int K, int w0) {
    __shared__ unsigned short Al[64][40];
    __shared__ unsigned short Bl[64][40];
    const int tid = threadIdx.x;
    const int n0 = blockIdx.x * 64, m0 = blockIdx.y * 64, bz = blockIdx.z;
    const int lane = tid & 63, wv = tid >> 6;
    const int wr = wv >> 1, wc = wv & 1;
    const int l15 = lane & 15, l4 = lane >> 4;
    f32x4 acc[2][2] = {};
    const int am = tid >> 2, ak = (tid & 3) * 8;
    const int bn = tid & 63, bk = (tid >> 6) * 8;
    int b_h = 0, b_wg = 0; bool b_ok = true;
    if constexpr (BMODE == 1) {
        int gn = n0 + bn; b_h = gn / PW; int wl = gn - b_h * PW; b_wg = w0 - 1 + wl;
        b_ok = (b_wg >= 0 && b_wg < L);
    }
    for (int k0 = 0; k0 < K; k0 += 32) {
        {
            unsigned short v[8];
            if constexpr (AMODE == 0) {
                const bft* A = (const bft*)Ap + (size_t)bz * zA
                             + (size_t)(m0 + am) * strideA + k0 + ak;
                *reinterpret_cast<uint4*>(v) = *reinterpret_cast<const uint4*>(A);
            } else if constexpr (AMODE == 1) {
                const float* A = (const float*)Ap + (size_t)bz * zA;
                int gm = m0 + am;
#pragma unroll
                for (int e = 0; e < 8; ++e) {
                    int gk = k0 + ak + e;
                    float f = (gm < Mreal && gk < Kreal)
                                  ? A[(size_t)gm * strideA + gk] : 0.f;
                    v[e] = f2bfu(f);
                }
            } else {
                const float* A = (const float*)Ap;
#pragma unroll
                for (int e = 0; e < 8; ++e)
                    v[e] = f2bfu(A[(size_t)(k0 + ak + e) * strideA + (m0 + am)]);
            }
            *reinterpret_cast<uint4*>(&Al[am][ak]) = *reinterpret_cast<uint4*>(v);
        }
        {
            unsigned short v[8];
            if constexpr (BMODE == 0) {
                const bft* B = (const bft*)Bp + (size_t)bz * zB
                             + (size_t)(k0 + bk) * strideB + n0 + bn;
#pragma unroll
                for (int e = 0; e < 8; ++e) v[e] = bfu(B + (size_t)e * strideB);
            } else if constexpr (BMODE == 1) {
                const bft* B = (const bft*)Bp + (size_t)(k0 + bk) * S
                             + (size_t)b_h * L + b_wg;
#pragma unroll
                for (int e = 0; e < 8; ++e)
                    v[e] = b_ok ? bfu(B + (size_t)e * S) : (unsigned short)0;
            } else if constexpr (BMODE == 2) {
                const float* B = (const float*)Bp + (size_t)(n0 + bn) * strideB + k0 + bk;
#pragma unroll
                for (int e = 0; e < 8; ++e) v[e] = f2bfu(B[e]);
            } else {
                const float* B = (const float*)Bp + (size_t)(k0 + bk) * strideB + n0 + bn;
#pragma unroll
                for (int e = 0; e < 8; ++e) v[e] = f2bfu(B[(size_t)e * strideB]);
            }
            *reinterpret_cast<uint4*>(&Bl[bn][bk]) = *reinterpret_cast<uint4*>(v);
        }
        __syncthreads();
        bf16x8 af[2], bf[2];
#pragma unroll
        for (int i = 0; i < 2; ++i) {
            af[i] = *reinterpret_cast<const bf16x8*>(&Al[wr * 32 + i * 16 + l15][l4 * 8]);
            bf[i] = *reinterpret_cast<const bf16x8*>(&Bl[wc * 32 + i * 16 + l15][l4 * 8]);
        }
#pragma unroll
        for (int i = 0; i < 2; ++i)
#pragma unroll
            for (int j = 0; j < 2; ++j)
                acc[i][j] = __builtin_amdgcn_mfma_f32_16x16x32_bf16(
                    af[i], bf[j], acc[i][j], 0, 0, 0);
        __syncthreads();
    }
#pragma unroll
    for (int i = 0; i < 2; ++i) {
        int mBase = m0 + wr * 32 + i * 16 + l4 * 4;
#pragma unroll
        for (int j = 0; j < 2; ++j) {
            int n = n0 + wc * 32 + j * 16 + l15;
#pragma unroll
            for (int r = 0; r < 4; ++r) {
                int m = mBase + r;
                float vv = acc[i][j][r];
                if constexpr (HASBIAS) vv += bias[m];
                size_t idx;
                if constexpr (OMODE == 0)
                    idx = (size_t)bz * zO + (size_t)m * strideO + n;
                else if constexpr (OMODE == 1) {
                    int h = n / SW, wl = n - h * SW;
                    idx = (size_t)m * S + (size_t)h * L + w0 + wl;
                } else {
                    int win = n >> 6, e = n & 63;
                    int hh = ((win / 24) << 3) + (e >> 3);
                    int ww = ((win % 24) << 3) + (e & 7);
                    idx = (size_t)m * S + (size_t)hh * L + ww;
                }
                if constexpr (HASRES) vv += ldf(Res + ((OMODE == 0)
                                  ? ((size_t)bz * zR + (size_t)m * strideO + n) : idx));
                stf(Out + idx, vv);
            }
        }
    }
}

// ---------------- depthwise 3x3 (spatial in) -> window-tiled out -------------
// in: [192][S] spatial bf16; out: [192][S] where col = win*64 + e
__global__ __launch_bounds__(BLK) void k_dwconv(const bft* __restrict__ in,
                                                const float* __restrict__ wt,
                                                bft* __restrict__ out) {
    int idx = blockIdx.x * BLK + threadIdx.x;    // [0, Cc*S)
    int ch = idx / S, s = idx - ch * S;
    int h = s / L, w = s - h * L;
    const float* wp = wt + (size_t)ch * 9;
    const bft* ip = in + (size_t)ch * S;
    float acc = 0.f;
#pragma unroll
    for (int dy = -1; dy <= 1; ++dy) {
        int hh = h + dy;
        if (hh < 0 || hh >= L) continue;
#pragma unroll
        for (int dx = -1; dx <= 1; ++dx) {
            int ww = w + dx;
            if (ww < 0 || ww >= L) continue;
            acc += wp[(dy + 1) * 3 + dx + 1] * __bfloat162float(ip[hh * L + ww]);
        }
    }
    int win = (h >> 3) * 24 + (w >> 3);
    int e = ((h & 7) << 3) + (w & 7);
    out[(size_t)ch * S + win * 64 + e] = __float2bfloat16(acc);
}

// ---------------- window channel attention (window-tiled in/out) -------------
// QW/KW/VW: [192][S] window-tiled bf16; out: same layout (k-region reuse)
__global__ __launch_bounds__(BLK) void k_attn(const bft* __restrict__ QW,
                                              const bft* __restrict__ KW,
                                              const bft* __restrict__ VW,
                                              const float* __restrict__ temp,
                                              bft* __restrict__ outp) {
    __shared__ float qs[32][65];
    __shared__ float ks[32][65];
    __shared__ float vs[32][65];
    __shared__ float at[32][33];
    const int win = blockIdx.x;
    const int hd = blockIdx.y;
    const int tid = threadIdx.x;
    const size_t base = (size_t)(hd * 32) * S + (size_t)win * 64;
#pragma unroll
    for (int i = 0; i < 8; ++i) {
        int idx = i * BLK + tid;
        int c = idx >> 6, e = idx & 63;
        size_t off = base + (size_t)c * S + e;
        qs[c][e] = __bfloat162float(QW[off]);
        ks[c][e] = __bfloat162float(KW[off]);
        vs[c][e] = __bfloat162float(VW[off]);
    }
    __syncthreads();
    const int r = tid >> 3, u = tid & 7;  // 32 rows x 8 lanes
    {
        float sq = 0.f, sk = 0.f;
#pragma unroll
        for (int j = 0; j < 8; ++j) {
            float a = qs[r][u + 8 * j]; sq += a * a;
            float c2 = ks[r][u + 8 * j]; sk += c2 * c2;
        }
#pragma unroll
        for (int m = 1; m < 8; m <<= 1) {
            sq += __shfl_xor(sq, m, 8);
            sk += __shfl_xor(sk, m, 8);
        }
        float fq = 1.f / fmaxf(sqrtf(sq), 1e-12f);
        float fk = 1.f / fmaxf(sqrtf(sk), 1e-12f);
#pragma unroll
        for (int j = 0; j < 8; ++j) {
            qs[r][u + 8 * j] *= fq;
            ks[r][u + 8 * j] *= fk;
        }
    }
    __syncthreads();
    {
        const int c = tid >> 3, dg = tid & 7;
        float a0 = 0.f, a1 = 0.f, a2 = 0.f, a3 = 0.f;
        for (int e = 0; e < 64; ++e) {
            float qv = qs[c][e];
            a0 += qv * ks[dg * 4 + 0][e];
            a1 += qv * ks[dg * 4 + 1][e];
            a2 += qv * ks[dg * 4 + 2][e];
            a3 += qv * ks[dg * 4 + 3][e];
        }
        float t = temp[hd];
        at[c][dg * 4 + 0] = a0 * t;
        at[c][dg * 4 + 1] = a1 * t;
        at[c][dg * 4 + 2] = a2 * t;
        at[c][dg * 4 + 3] = a3 * t;
    }
    __syncthreads();
    {
        float mx = -1e30f;
#pragma unroll
        for (int j = 0; j < 4; ++j) mx = fmaxf(mx, at[r][u + 8 * j]);
#pragma unroll
        for (int m = 1; m < 8; m <<= 1) mx = fmaxf(mx, __shfl_xor(mx, m, 8));
        float pv[4], sm = 0.f;
#pragma unroll
        for (int j = 0; j < 4; ++j) {
            pv[j] = __expf(at[r][u + 8 * j] - mx);
            sm += pv[j];
        }
#pragma unroll
        for (int m = 1; m < 8; m <<= 1) sm += __shfl_xor(sm, m, 8);
        float inv = 1.f / sm;
#pragma unroll
        for (int j = 0; j < 4; ++j) at[r][u + 8 * j] = pv[j] * inv;
    }
    __syncthreads();
    {
        const int c = tid >> 3;
        float o[8];
#pragma unroll
        for (int j = 0; j < 8; ++j) o[j] = 0.f;
        for (int d = 0; d < 32; ++d) {
            float a = at[c][d];
#pragma unroll
            for (int j = 0; j < 8; ++j) o[j] += a * vs[d][u * 8 + j];
        }
        unsigned short ov[8];
#pragma unroll
        for (int j = 0; j < 8; ++j) ov[j] = f2bfu(o[j]);
        *reinterpret_cast<uint4*>(outp + base + (size_t)c * S + u * 8) =
            *reinterpret_cast<uint4*>(ov);
    }
}

// ---------------- FFN gate on strip (vectorized, 8 outputs/thread) -----------
__global__ __launch_bounds__(BLK) void k_gate(const bft* __restrict__ f,
                                              const float* __restrict__ wt,
                                              bft* __restrict__ g) {
    const int NS = L * PW, NG = L * SW;  // 9600, 9216
    int t = blockIdx.x * BLK + threadIdx.x;       // HID * L * 6
    int c = t / (L * 6);
    int rr = t - c * (L * 6);
    int h = rr / 6, wl0 = (rr - h * 6) * 8;
    const bft* f1 = f + (size_t)c * NS;
    const bft* f2 = f + (size_t)(c + HID) * NS;
    float w1[9], w2[9];
#pragma unroll
    for (int i = 0; i < 9; ++i) {
        w1[i] = wt[(size_t)c * 9 + i];
        w2[i] = wt[((size_t)c + HID) * 9 + i];
    }
    float a1[8], a2[8];
#pragma unroll
    for (int j = 0; j < 8; ++j) { a1[j] = 0.f; a2[j] = 0.f; }
#pragma unroll
    for (int dy = 0; dy < 3; ++dy) {
        int hh = h + dy - 1;
        if (hh < 0 || hh >= L) continue;
        float e1[10], e2[10];
        const unsigned int* p1 =
            reinterpret_cast<const unsigned int*>(f1 + (size_t)hh * PW + wl0);
        const unsigned int* p2 =
            reinterpret_cast<const unsigned int*>(f2 + (size_t)hh * PW + wl0);
#pragma unroll
        for (int q = 0; q < 5; ++q) {
            unsigned int d1 = p1[q], d2 = p2[q];
            e1[2 * q]     = bu2f((unsigned short)(d1 & 0xffff));
            e1[2 * q + 1] = bu2f((unsigned short)(d1 >> 16));
            e2[2 * q]     = bu2f((unsigned short)(d2 & 0xffff));
            e2[2 * q + 1] = bu2f((unsigned short)(d2 >> 16));
        }
#pragma unroll
        for (int dx = 0; dx < 3; ++dx) {
            float ww1 = w1[dy * 3 + dx], ww2 = w2[dy * 3 + dx];
#pragma unroll
            for (int j = 0; j < 8; ++j) {
                a1[j] += ww1 * e1[j + dx];
                a2[j] += ww2 * e2[j + dx];
            }
        }
    }
    unsigned short ov[8];
#pragma unroll
    for (int j = 0; j < 8; ++j) {
        float ge = 0.5f * a1[j] * (1.f + erff(a1[j] * 0.70710678118654752f));
        ov[j] = f2bfu(ge * a2[j]);
    }
    *reinterpret_cast<uint4*>(g + (size_t)c * NG + (size_t)h * SW + wl0) =
        *reinterpret_cast<uint4*>(ov);
}

// -----------------------------------------------------------------------------
extern "C" void kernel_launch(void* const* d_in, const int* in_sizes, int n_in,
                              void* d_out, int out_size, void* d_ws, size_t ws_size,
                              hipStream_t stream) {
    const float* x      = (const float*)d_in[0];
    const float* n1w    = (const float*)d_in[1];
    const float* n1b    = (const float*)d_in[2];
    const float* w_qkv  = (const float*)d_in[3];
    const float* w_dw   = (const float*)d_in[4];
    const float* temp   = (const float*)d_in[5];
    const float* w_proj = (const float*)d_in[6];
    const float* b_proj = (const float*)d_in[7];
    const float* n2w    = (const float*)d_in[8];
    const float* n2b    = (const float*)d_in[9];
    const float* w_in   = (const float*)d_in[10];
    const float* w_dwf  = (const float*)d_in[11];
    const float* w_out  = (const float*)d_in[12];
    float* outp = (float*)d_out;

    // workspace layout (99,237,888 bytes total — identical to round 4/5)
    const size_t DCT_B = 147456;
    const size_t CS    = (size_t)Cc * S;
    const size_t X1_B  = (size_t)Bn * CS * 2;
    const size_t P_B   = CS * 2;
    const size_t NEED  = DCT_B + X1_B + 2 * P_B + (size_t)3 * CS * 2;
    if (ws_size < NEED) return;

    char* p = (char*)d_ws;
    float* dct = (float*)p;                p += DCT_B;
    bft* X1    = (bft*)p;                  p += X1_B;
    bft* Pb    = (bft*)p;                  p += P_B;
    bft* Qb    = (bft*)p;                  p += P_B;
    bft* QKV   = (bft*)p;                  // 3 * CS bf16 (also f region in FFN)
    bft* fbuf  = QKV;
    bft* gstrip = Qb;

    k_dct_init<<<144, BLK, 0, stream>>>(dct);

    for (int b = 0; b < Bn; ++b) {
        const float* xb = x + (size_t)b * CS;
        bft* x1b = X1 + (size_t)b * CS;
        // LN1
        k_ln<float><<<S / BLK, BLK, 0, stream>>>(xb, n1w, n1b, Pb);
        // t = Mh @ Y (batched over c)
        k_gemm<1, 0, 0, false, false, bft, float><<<dim3(3, 3, Cc), BLK, 0, stream>>>(
            dct, L, L, L, 0,  Pb, L, S,  Qb, L, S,  nullptr, nullptr, 0,  L, 0);
        // yd = T @ Mw^T (flattened)
        k_gemm<0, 2, 0, false, false, bft, float><<<dim3(3, 576, 1), BLK, 0, stream>>>(
            Qb, L, 0, 0, 0,  dct, L, 0,  Pb, L, 0,  nullptr, nullptr, 0,  L, 0);
        // qkv = W_qkv @ yd -> QKV spatial [576][S]
        k_gemm<1, 0, 0, false, false, bft, float><<<dim3(576, 9, 1), BLK, 0, stream>>>(
            w_qkv, Cc, 576, Cc, 0,  Pb, S, 0,  QKV, S, 0,  nullptr, nullptr, 0,  Cc, 0);
        // depthwise 3x3 per z -> window-tiled: q->Pb, k->Qb, v->QKV[0:192]
        k_dwconv<<<(Cc * S) / BLK, BLK, 0, stream>>>(QKV, w_dw, Pb);
        k_dwconv<<<(Cc * S) / BLK, BLK, 0, stream>>>(QKV + CS, w_dw + Cc * 9, Qb);
        k_dwconv<<<(Cc * S) / BLK, BLK, 0, stream>>>(QKV + 2 * CS, w_dw + 2 * Cc * 9, QKV);
        // attention -> window-tiled out in QKV[192:384] region
        k_attn<<<dim3(576, 6), BLK, 0, stream>>>(Pb, Qb, QKV, temp, QKV + CS);
        // proj + bias, decode window-tiled cols -> spatial Pb
        k_gemm<1, 0, 2, true, false, bft, float><<<dim3(576, 3, 1), BLK, 0, stream>>>(
            w_proj, Cc, Cc, Cc, 0,  QKV + CS, S, 0,  Pb, S, 0,  b_proj, nullptr, 0,  Cc, 0);
        // u = P @ Mw (flattened)
        k_gemm<0, 3, 0, false, false, bft, float><<<dim3(3, 576, 1), BLK, 0, stream>>>(
            Pb, L, 0, 0, 0,  dct, L, 0,  Qb, L, 0,  nullptr, nullptr, 0,  L, 0);
        // x1 = Mh^T @ U + x (batched over c)
        k_gemm<2, 0, 0, false, true, bft, float><<<dim3(3, 3, Cc), BLK, 0, stream>>>(
            dct, L, 0, 0, 0,  Qb, L, S,  x1b, L, S,  nullptr, xb, S,  L, 0);
    }
    for (int b = 0; b < Bn; ++b) {
        bft* x1b = X1 + (size_t)b * CS;
        float* outb = outp + (size_t)b * CS;
        // LN2
        k_ln<bft><<<S / BLK, BLK, 0, stream>>>(x1b, n2w, n2b, Pb);
        for (int st = 0; st < 4; ++st) {
            int w0 = st * SW;
            // f = W_in @ z (strip, halo)
            k_gemm<1, 1, 0, false, false, bft, float><<<dim3(150, 16, 1), BLK, 0, stream>>>(
                w_in, Cc, 2 * HID, Cc, 0,  Pb, S, 0,  fbuf, L * PW, 0,
                nullptr, nullptr, 0,  Cc, w0);
            // gated dwconv + GELU (vectorized)
            k_gate<<<(HID * L * 6) / BLK, BLK, 0, stream>>>(fbuf, w_dwf, gstrip);
            // out = W_out @ g + x1 (strip out)
            k_gemm<1, 0, 1, false, true, float, bft><<<dim3(144, 3, 1), BLK, 0, stream>>>(
                w_out, HID, Cc, HID, 0,  gstrip, L * SW, 0,  outb, 0, 0,
                nullptr, x1b, 0,  512, w0);
        }
    }
}

// Round 7
// 1055.955 us; speedup vs baseline: 2.2569x; 1.8266x over previous
//
#include <hip/hip_runtime.h>
#include <hip/hip_bf16.h>

typedef __hip_bfloat16 bft;
typedef __attribute__((ext_vector_type(8))) short bf16x8;
typedef __attribute__((ext_vector_type(4))) float f32x4;

#define BLK 256
static constexpr int Cc = 192;     // channels
static constexpr int L  = 192;     // H = W
static constexpr int S  = 36864;   // L*L
static constexpr int Bn = 2;       // batch
static constexpr int HID = 510;    // int(192*2.66)
static constexpr int PW = 50;      // FFN strip width incl. halo
static constexpr int SW = 48;      // FFN strip output width
static constexpr double PI_D = 3.141592653589793238462643383279502884;

__device__ __forceinline__ float ldf(const float* p) { return *p; }
__device__ __forceinline__ float ldf(const bft* p)   { return __bfloat162float(*p); }
__device__ __forceinline__ void  stf(float* p, float v) { *p = v; }
__device__ __forceinline__ void  stf(bft* p, float v)   { *p = __float2bfloat16(v); }
__device__ __forceinline__ unsigned short f2bfu(float f) {
    bft h = __float2bfloat16(f);
    return *reinterpret_cast<const unsigned short*>(&h);
}
__device__ __forceinline__ unsigned short bfu(const bft* p) {
    return *reinterpret_cast<const unsigned short*>(p);
}
__device__ __forceinline__ float bu2f(unsigned short u) {
    unsigned int x = (unsigned int)u << 16;
    return __uint_as_float(x);
}

// ---------------- DCT matrix init -> bf16 direct + transposed ----------------
__global__ __launch_bounds__(BLK) void k_dct_init(bft* __restrict__ dctb,
                                                  bft* __restrict__ dctTb) {
    int idx = blockIdx.x * BLK + threadIdx.x;
    if (idx >= L * L) return;
    int p = idx / L, h = idx - p * L;
    double v = (p == 0) ? sqrt(1.0 / L)
                        : cos(PI_D * p * (2 * h + 1) / (2.0 * L)) * sqrt(2.0 / L);
    bft bv = __float2bfloat16((float)v);
    dctb[p * L + h] = bv;
    dctTb[h * L + p] = bv;
}

// ---------------- fp32 weight -> bf16 with zero pad --------------------------
__global__ __launch_bounds__(BLK) void k_cvt(const float* __restrict__ src,
                                             bft* __restrict__ dst,
                                             int Mr, int Kr, int Kp) {
    int idx = blockIdx.x * BLK + threadIdx.x;   // [0, Mp*Kp)
    int m = idx / Kp, k = idx - m * Kp;
    float v = (m < Mr && k < Kr) ? src[(size_t)m * Kr + k] : 0.f;
    dst[idx] = __float2bfloat16(v);
}

// ---------------- LayerNorm over channel dim (per batch) ---------------------
template <typename TI>
__global__ __launch_bounds__(BLK) void k_ln(const TI* __restrict__ x,
                                            const float* __restrict__ w,
                                            const float* __restrict__ b,
                                            bft* __restrict__ out) {
    int s = blockIdx.x * BLK + threadIdx.x;   // [0, S)
    const TI* xp = x + s;
    float sum = 0.f, sq = 0.f;
    for (int c = 0; c < Cc; ++c) {
        float v = ldf(xp + (size_t)c * S);
        sum += v; sq += v * v;
    }
    float mu = sum * (1.f / Cc);
    float var = sq * (1.f / Cc) - mu * mu;
    float r = rsqrtf(var + 1e-5f);
    for (int c = 0; c < Cc; ++c) {
        float v = ldf(xp + (size_t)c * S);
        stf(out + s + (size_t)c * S, (v - mu) * r * w[c] + b[c]);
    }
}

// =============================================================================
// Unified MFMA bf16 GEMM. Block = (WR*FM*16) x (WC*FN*16), 4 waves (WR x WC),
// BK=32. All operands bf16 (weights pre-converted).
//   BMODE: 0 = bf16 [k][n] strideB (+zB batch); 1 = FFN strip gather from [k][S]
//   OMODE: 0 = linear; 1 = FFN strip scatter; 2 = window-tiled -> spatial
// =============================================================================
template <int WR, int WC, int FM, int FN, int BMODE, int OMODE,
          bool HASBIAS, bool HASRES, typename OutT, typename ResT>
__global__ __launch_bounds__(256) void k_mm(
    const bft* __restrict__ A, int strideA, int Mreal, long zA,
    const bft* __restrict__ B, int strideB, long zB,
    OutT* __restrict__ Out, int strideO, long zO,
    const float* __restrict__ bias,
    const ResT* __restrict__ Res, long zR,
    int K, int w0) {
    constexpr int BM = WR * FM * 16, BN = WC * FN * 16;
    __shared__ unsigned short Al[BM][40];
    __shared__ unsigned short Bl[BN][40];
    const int tid = threadIdx.x;
    const int n0 = blockIdx.x * BN, m0 = blockIdx.y * BM, bz = blockIdx.z;
    const int lane = tid & 63, wv = tid >> 6;
    const int wr = wv / WC, wc = wv % WC;
    const int l15 = lane & 15, l4 = lane >> 4;
    f32x4 acc[FM][FN] = {};

    // A staging: each thread AE k-contig elems of one row
    constexpr int AE = BM / 8;             // 16 (BM=128) or 8 (BM=64)
    constexpr int TPR = 256 / BM;          // threads per row
    const int arow = tid / TPR, akc = (tid % TPR) * AE;
    // B staging: each thread BE k-values at one n (transposed store)
    int bn, bk; bool bact = true;
    if constexpr (BN == 128) { bn = tid & 127; bk = (tid >> 7) * 16; }
    else                     { bn = tid; bk = 0; bact = (tid < BN); }
    constexpr int BE = (BN == 128) ? 16 : 32;
    int b_h = 0, b_wg = 0; bool b_ok = true;
    if constexpr (BMODE == 1) {
        int gn = n0 + bn; b_h = gn / PW; int wl = gn - b_h * PW; b_wg = w0 - 1 + wl;
        b_ok = (b_wg >= 0 && b_wg < L);
    }

    const bft* Ab = A + (size_t)bz * zA;
    const bft* Bb = B + (size_t)bz * zB;
    int gm = m0 + arow; if (gm >= Mreal) gm = Mreal - 1;   // clamp, epilogue masks

    for (int k0 = 0; k0 < K; k0 += 32) {
        {   // stage A
            const bft* src = Ab + (size_t)gm * strideA + k0 + akc;
#pragma unroll
            for (int q = 0; q < AE / 8; ++q)
                *reinterpret_cast<uint4*>(&Al[arow][akc + 8 * q]) =
                    *reinterpret_cast<const uint4*>(src + 8 * q);
        }
        if (bact) {  // stage B transposed
            unsigned short v[BE];
            if constexpr (BMODE == 0) {
                const bft* src = Bb + (size_t)(k0 + bk) * strideB + n0 + bn;
#pragma unroll
                for (int e = 0; e < BE; ++e) v[e] = bfu(src + (size_t)e * strideB);
            } else {
                const bft* src = Bb + (size_t)(k0 + bk) * S + (size_t)b_h * L + b_wg;
#pragma unroll
                for (int e = 0; e < BE; ++e)
                    v[e] = b_ok ? bfu(src + (size_t)e * S) : (unsigned short)0;
            }
#pragma unroll
            for (int q = 0; q < BE / 8; ++q)
                *reinterpret_cast<uint4*>(&Bl[bn][bk + 8 * q]) =
                    *reinterpret_cast<uint4*>(&v[8 * q]);
        }
        __syncthreads();
        bf16x8 af[FM], bf[FN];
#pragma unroll
        for (int i = 0; i < FM; ++i)
            af[i] = *reinterpret_cast<const bf16x8*>(
                &Al[wr * FM * 16 + i * 16 + l15][l4 * 8]);
#pragma unroll
        for (int j = 0; j < FN; ++j)
            bf[j] = *reinterpret_cast<const bf16x8*>(
                &Bl[wc * FN * 16 + j * 16 + l15][l4 * 8]);
#pragma unroll
        for (int i = 0; i < FM; ++i)
#pragma unroll
            for (int j = 0; j < FN; ++j)
                acc[i][j] = __builtin_amdgcn_mfma_f32_16x16x32_bf16(
                    af[i], bf[j], acc[i][j], 0, 0, 0);
        __syncthreads();
    }
#pragma unroll
    for (int i = 0; i < FM; ++i) {
        int mB = m0 + wr * FM * 16 + i * 16 + l4 * 4;
#pragma unroll
        for (int j = 0; j < FN; ++j) {
            int n = n0 + wc * FN * 16 + j * 16 + l15;
#pragma unroll
            for (int r = 0; r < 4; ++r) {
                int m = mB + r;
                if (m >= Mreal) continue;
                float vv = acc[i][j][r];
                if constexpr (HASBIAS) vv += bias[m];
                size_t idx;
                if constexpr (OMODE == 0)
                    idx = (size_t)bz * zO + (size_t)m * strideO + n;
                else if constexpr (OMODE == 1) {
                    int h = n / SW, wl = n - h * SW;
                    idx = (size_t)m * S + (size_t)h * L + w0 + wl;
                } else {
                    int win = n >> 6, e = n & 63;
                    int hh = ((win / 24) << 3) + (e >> 3);
                    int ww = ((win % 24) << 3) + (e & 7);
                    idx = (size_t)m * S + (size_t)hh * L + ww;
                }
                if constexpr (HASRES) vv += ldf(Res + ((OMODE == 0)
                                  ? ((size_t)bz * zR + (size_t)m * strideO + n) : idx));
                stf(Out + idx, vv);
            }
        }
    }
}

// ---------------- depthwise 3x3 (8 outputs/thread) -> window-tiled -----------
__global__ __launch_bounds__(BLK) void k_dwconv(const bft* __restrict__ in,
                                                const float* __restrict__ wt,
                                                bft* __restrict__ out) {
    int t = blockIdx.x * BLK + threadIdx.x;      // [0, Cc*S/8)
    int ch = t / (S / 8);
    int rem = t - ch * (S / 8);
    int h = rem / 24, wb = (rem - h * 24) * 8;
    const float* wp = wt + (size_t)ch * 9;
    const bft* ip = in + (size_t)ch * S;
    float acc[8] = {};
#pragma unroll
    for (int dy = -1; dy <= 1; ++dy) {
        int hh = h + dy;
        if (hh < 0 || hh >= L) continue;
        const bft* rp = ip + hh * L + wb;
        float e[10];
        uint4 mid = *reinterpret_cast<const uint4*>(rp);
        const unsigned short* ms = reinterpret_cast<const unsigned short*>(&mid);
#pragma unroll
        for (int q = 0; q < 8; ++q) e[q + 1] = bu2f(ms[q]);
        e[0] = (wb > 0) ? ldf(rp - 1) : 0.f;
        e[9] = (wb + 8 < L) ? ldf(rp + 8) : 0.f;
        float c0 = wp[(dy + 1) * 3], c1 = wp[(dy + 1) * 3 + 1], c2 = wp[(dy + 1) * 3 + 2];
#pragma unroll
        for (int q = 0; q < 8; ++q)
            acc[q] += c0 * e[q] + c1 * e[q + 1] + c2 * e[q + 2];
    }
    int win = (h >> 3) * 24 + (wb >> 3);
    int e0 = (h & 7) * 8;
    unsigned short ov[8];
#pragma unroll
    for (int q = 0; q < 8; ++q) ov[q] = f2bfu(acc[q]);
    *reinterpret_cast<uint4*>(out + (size_t)ch * S + win * 64 + e0) =
        *reinterpret_cast<uint4*>(ov);
}

// ---------------- window channel attention (window-tiled in/out) -------------
__global__ __launch_bounds__(BLK) void k_attn(const bft* __restrict__ QW,
                                              const bft* __restrict__ KW,
                                              const bft* __restrict__ VW,
                                              const float* __restrict__ temp,
                                              bft* __restrict__ outp) {
    __shared__ float qs[32][65];
    __shared__ float ks[32][65];
    __shared__ float vs[32][65];
    __shared__ float at[32][33];
    const int win = blockIdx.x;
    const int hd = blockIdx.y;
    const int tid = threadIdx.x;
    const size_t base = (size_t)(hd * 32) * S + (size_t)win * 64;
#pragma unroll
    for (int i = 0; i < 8; ++i) {
        int idx = i * BLK + tid;
        int c = idx >> 6, e = idx & 63;
        size_t off = base + (size_t)c * S + e;
        qs[c][e] = __bfloat162float(QW[off]);
        ks[c][e] = __bfloat162float(KW[off]);
        vs[c][e] = __bfloat162float(VW[off]);
    }
    __syncthreads();
    const int r = tid >> 3, u = tid & 7;
    {
        float sq = 0.f, sk = 0.f;
#pragma unroll
        for (int j = 0; j < 8; ++j) {
            float a = qs[r][u + 8 * j]; sq += a * a;
            float c2 = ks[r][u + 8 * j]; sk += c2 * c2;
        }
#pragma unroll
        for (int m = 1; m < 8; m <<= 1) {
            sq += __shfl_xor(sq, m, 8);
            sk += __shfl_xor(sk, m, 8);
        }
        float fq = 1.f / fmaxf(sqrtf(sq), 1e-12f);
        float fk = 1.f / fmaxf(sqrtf(sk), 1e-12f);
#pragma unroll
        for (int j = 0; j < 8; ++j) {
            qs[r][u + 8 * j] *= fq;
            ks[r][u + 8 * j] *= fk;
        }
    }
    __syncthreads();
    {
        const int c = tid >> 3, dg = tid & 7;
        float a0 = 0.f, a1 = 0.f, a2 = 0.f, a3 = 0.f;
        for (int e = 0; e < 64; ++e) {
            float qv = qs[c][e];
            a0 += qv * ks[dg * 4 + 0][e];
            a1 += qv * ks[dg * 4 + 1][e];
            a2 += qv * ks[dg * 4 + 2][e];
            a3 += qv * ks[dg * 4 + 3][e];
        }
        float t = temp[hd];
        at[c][dg * 4 + 0] = a0 * t;
        at[c][dg * 4 + 1] = a1 * t;
        at[c][dg * 4 + 2] = a2 * t;
        at[c][dg * 4 + 3] = a3 * t;
    }
    __syncthreads();
    {
        float mx = -1e30f;
#pragma unroll
        for (int j = 0; j < 4; ++j) mx = fmaxf(mx, at[r][u + 8 * j]);
#pragma unroll
        for (int m = 1; m < 8; m <<= 1) mx = fmaxf(mx, __shfl_xor(mx, m, 8));
        float pv[4], sm = 0.f;
#pragma unroll
        for (int j = 0; j < 4; ++j) {
            pv[j] = __expf(at[r][u + 8 * j] - mx);
            sm += pv[j];
        }
#pragma unroll
        for (int m = 1; m < 8; m <<= 1) sm += __shfl_xor(sm, m, 8);
        float inv = 1.f / sm;
#pragma unroll
        for (int j = 0; j < 4; ++j) at[r][u + 8 * j] = pv[j] * inv;
    }
    __syncthreads();
    {
        const int c = tid >> 3;
        float o[8];
#pragma unroll
        for (int j = 0; j < 8; ++j) o[j] = 0.f;
        for (int d = 0; d < 32; ++d) {
            float a = at[c][d];
#pragma unroll
            for (int j = 0; j < 8; ++j) o[j] += a * vs[d][u * 8 + j];
        }
        unsigned short ov[8];
#pragma unroll
        for (int j = 0; j < 8; ++j) ov[j] = f2bfu(o[j]);
        *reinterpret_cast<uint4*>(outp + base + (size_t)c * S + u * 8) =
            *reinterpret_cast<uint4*>(ov);
    }
}

// ---------------- FFN gate on strip (vectorized, 8 outputs/thread) -----------
__global__ __launch_bounds__(BLK) void k_gate(const bft* __restrict__ f,
                                              const float* __restrict__ wt,
                                              bft* __restrict__ g) {
    const int NS = L * PW, NG = L * SW;  // 9600, 9216
    int t = blockIdx.x * BLK + threadIdx.x;       // HID * L * 6
    int c = t / (L * 6);
    int rr = t - c * (L * 6);
    int h = rr / 6, wl0 = (rr - h * 6) * 8;
    const bft* f1 = f + (size_t)c * NS;
    const bft* f2 = f + (size_t)(c + HID) * NS;
    float w1[9], w2[9];
#pragma unroll
    for (int i = 0; i < 9; ++i) {
        w1[i] = wt[(size_t)c * 9 + i];
        w2[i] = wt[((size_t)c + HID) * 9 + i];
    }
    float a1[8], a2[8];
#pragma unroll
    for (int j = 0; j < 8; ++j) { a1[j] = 0.f; a2[j] = 0.f; }
#pragma unroll
    for (int dy = 0; dy < 3; ++dy) {
        int hh = h + dy - 1;
        if (hh < 0 || hh >= L) continue;
        float e1[10], e2[10];
        const unsigned int* p1 =
            reinterpret_cast<const unsigned int*>(f1 + (size_t)hh * PW + wl0);
        const unsigned int* p2 =
            reinterpret_cast<const unsigned int*>(f2 + (size_t)hh * PW + wl0);
#pragma unroll
        for (int q = 0; q < 5; ++q) {
            unsigned int d1 = p1[q], d2 = p2[q];
            e1[2 * q]     = bu2f((unsigned short)(d1 & 0xffff));
            e1[2 * q + 1] = bu2f((unsigned short)(d1 >> 16));
            e2[2 * q]     = bu2f((unsigned short)(d2 & 0xffff));
            e2[2 * q + 1] = bu2f((unsigned short)(d2 >> 16));
        }
#pragma unroll
        for (int dx = 0; dx < 3; ++dx) {
            float ww1 = w1[dy * 3 + dx], ww2 = w2[dy * 3 + dx];
#pragma unroll
            for (int j = 0; j < 8; ++j) {
                a1[j] += ww1 * e1[j + dx];
                a2[j] += ww2 * e2[j + dx];
            }
        }
    }
    unsigned short ov[8];
#pragma unroll
    for (int j = 0; j < 8; ++j) {
        float ge = 0.5f * a1[j] * (1.f + erff(a1[j] * 0.70710678118654752f));
        ov[j] = f2bfu(ge * a2[j]);
    }
    *reinterpret_cast<uint4*>(g + (size_t)c * NG + (size_t)h * SW + wl0) =
        *reinterpret_cast<uint4*>(ov);
}

// -----------------------------------------------------------------------------
extern "C" void kernel_launch(void* const* d_in, const int* in_sizes, int n_in,
                              void* d_out, int out_size, void* d_ws, size_t ws_size,
                              hipStream_t stream) {
    const float* x      = (const float*)d_in[0];
    const float* n1w    = (const float*)d_in[1];
    const float* n1b    = (const float*)d_in[2];
    const float* w_qkv  = (const float*)d_in[3];
    const float* w_dw   = (const float*)d_in[4];
    const float* temp   = (const float*)d_in[5];
    const float* w_proj = (const float*)d_in[6];
    const float* b_proj = (const float*)d_in[7];
    const float* n2w    = (const float*)d_in[8];
    const float* n2b    = (const float*)d_in[9];
    const float* w_in   = (const float*)d_in[10];
    const float* w_dwf  = (const float*)d_in[11];
    const float* w_out  = (const float*)d_in[12];
    float* outp = (float*)d_out;

    // workspace layout: 100,122,624 bytes
    const size_t DCT_B = 147456;                       // dctb + dctTb (bf16)
    const size_t CS    = (size_t)Cc * S;
    const size_t X1_B  = (size_t)Bn * CS * 2;
    const size_t P_B   = CS * 2;
    const size_t WB_B  = 884736;                       // bf16 weight cache
    const size_t NEED  = DCT_B + X1_B + 2 * P_B + (size_t)3 * CS * 2 + WB_B;
    if (ws_size < NEED) return;

    char* p = (char*)d_ws;
    bft* dctb  = (bft*)p;                  // [192][192]
    bft* dctTb = dctb + L * L;             // [192][192]
    p += DCT_B;
    bft* X1    = (bft*)p;                  p += X1_B;
    bft* Pb    = (bft*)p;                  p += P_B;
    bft* Qb    = (bft*)p;                  p += P_B;
    bft* QKV   = (bft*)p;                  p += 3 * CS * 2;
    bft* w_qkv_b = (bft*)p;                // 576*192
    bft* w_proj_b = w_qkv_b + 576 * 192;   // 192*192
    bft* w_in_b  = w_proj_b + 192 * 192;   // 1024*192 (pad M)
    bft* w_out_b = w_in_b + 1024 * 192;    // 192*512 (pad K)
    bft* fbuf  = QKV;                      // 1024 x 9600
    bft* gstrip = Qb;                      // 512 x 9216

    // prep: dct + weight conversion (once)
    k_dct_init<<<144, BLK, 0, stream>>>(dctb, dctTb);
    k_cvt<<<432, BLK, 0, stream>>>(w_qkv, w_qkv_b, 576, 192, 192);
    k_cvt<<<144, BLK, 0, stream>>>(w_proj, w_proj_b, 192, 192, 192);
    k_cvt<<<768, BLK, 0, stream>>>(w_in, w_in_b, 1020, 192, 192);
    k_cvt<<<384, BLK, 0, stream>>>(w_out, w_out_b, 192, 510, 512);

    for (int b = 0; b < Bn; ++b) {
        const float* xb = x + (size_t)b * CS;
        bft* x1b = X1 + (size_t)b * CS;
        k_ln<float><<<S / BLK, BLK, 0, stream>>>(xb, n1w, n1b, Pb);
        // t = Mh @ Y (batched over c)  [64x192 tile]
        k_mm<1, 4, 4, 3, 0, 0, false, false, bft, float><<<dim3(1, 3, Cc), 256, 0, stream>>>(
            dctb, L, L, 0,  Pb, L, S,  Qb, L, S,  nullptr, nullptr, 0,  L, 0);
        // yd = T @ Mw^T (flattened M=36864)
        k_mm<1, 4, 4, 3, 0, 0, false, false, bft, float><<<dim3(1, 576, 1), 256, 0, stream>>>(
            Qb, L, S * Cc / L, 0,  dctTb, L, 0,  Pb, L, 0,  nullptr, nullptr, 0,  L, 0);
        // qkv = W_qkv @ yd  [128x128 tile]
        k_mm<2, 2, 4, 4, 0, 0, false, false, bft, float><<<dim3(288, 5, 1), 256, 0, stream>>>(
            w_qkv_b, Cc, 576, 0,  Pb, S, 0,  QKV, S, 0,  nullptr, nullptr, 0,  Cc, 0);
        // depthwise 3x3 -> window-tiled: q->Pb, k->Qb, v->QKV[0:CS]
        k_dwconv<<<(Cc * S / 8) / BLK, BLK, 0, stream>>>(QKV, w_dw, Pb);
        k_dwconv<<<(Cc * S / 8) / BLK, BLK, 0, stream>>>(QKV + CS, w_dw + Cc * 9, Qb);
        k_dwconv<<<(Cc * S / 8) / BLK, BLK, 0, stream>>>(QKV + 2 * CS, w_dw + 2 * Cc * 9, QKV);
        // attention -> QKV[CS:2CS] (window-tiled)
        k_attn<<<dim3(576, 6), BLK, 0, stream>>>(Pb, Qb, QKV, temp, QKV + CS);
        // proj + bias, window decode -> Pb spatial(dct coords)
        k_mm<2, 2, 4, 4, 0, 2, true, false, bft, float><<<dim3(288, 2, 1), 256, 0, stream>>>(
            w_proj_b, Cc, Cc, 0,  QKV + CS, S, 0,  Pb, S, 0,  b_proj, nullptr, 0,  Cc, 0);
        // u = P @ Mw (flattened)
        k_mm<1, 4, 4, 3, 0, 0, false, false, bft, float><<<dim3(1, 576, 1), 256, 0, stream>>>(
            Pb, L, S * Cc / L, 0,  dctb, L, 0,  Qb, L, 0,  nullptr, nullptr, 0,  L, 0);
        // x1 = Mh^T @ U + x (batched over c)
        k_mm<1, 4, 4, 3, 0, 0, false, true, bft, float><<<dim3(1, 3, Cc), 256, 0, stream>>>(
            dctTb, L, L, 0,  Qb, L, S,  x1b, L, S,  nullptr, xb, S,  L, 0);
    }
    for (int b = 0; b < Bn; ++b) {
        bft* x1b = X1 + (size_t)b * CS;
        float* outb = outp + (size_t)b * CS;
        k_ln<bft><<<S / BLK, BLK, 0, stream>>>(x1b, n2w, n2b, Pb);
        for (int st = 0; st < 4; ++st) {
            int w0 = st * SW;
            // f = W_in @ z (strip gather)
            k_mm<2, 2, 4, 4, 1, 0, false, false, bft, float><<<dim3(75, 8, 1), 256, 0, stream>>>(
                w_in_b, Cc, 1024, 0,  Pb, S, 0,  fbuf, L * PW, 0,
                nullptr, nullptr, 0,  Cc, w0);
            // gated dwconv + GELU
            k_gate<<<(HID * L * 6) / BLK, BLK, 0, stream>>>(fbuf, w_dwf, gstrip);
            // out = W_out @ g + x1 (strip scatter, fp32 out)
            k_mm<2, 2, 4, 4, 0, 1, false, true, float, bft><<<dim3(72, 2, 1), 256, 0, stream>>>(
                w_out_b, 512, Cc, 0,  gstrip, L * SW, 0,  outb, 0, 0,
                nullptr, x1b, 0,  512, w0);
        }
    }
}

// Round 8
// 963.174 us; speedup vs baseline: 2.4744x; 1.0963x over previous
//
#include <hip/hip_runtime.h>
#include <hip/hip_bf16.h>

typedef __hip_bfloat16 bft;
typedef __attribute__((ext_vector_type(8))) short bf16x8;
typedef __attribute__((ext_vector_type(4))) float f32x4;

#define BLK 256
static constexpr int Cc = 192;     // channels
static constexpr int L  = 192;     // H = W
static constexpr int S  = 36864;   // L*L
static constexpr int Bn = 2;       // batch
static constexpr int HID = 510;    // int(192*2.66)
static constexpr int PW = 50;      // FFN strip width incl. halo
static constexpr int SW = 48;      // FFN strip output width
static constexpr double PI_D = 3.141592653589793238462643383279502884;

__device__ __forceinline__ float ldf(const float* p) { return *p; }
__device__ __forceinline__ float ldf(const bft* p)   { return __bfloat162float(*p); }
__device__ __forceinline__ void  stf(float* p, float v) { *p = v; }
__device__ __forceinline__ void  stf(bft* p, float v)   { *p = __float2bfloat16(v); }
__device__ __forceinline__ unsigned short f2bfu(float f) {
    bft h = __float2bfloat16(f);
    return *reinterpret_cast<const unsigned short*>(&h);
}
__device__ __forceinline__ unsigned short bfu(const bft* p) {
    return *reinterpret_cast<const unsigned short*>(p);
}
__device__ __forceinline__ float bu2f(unsigned short u) {
    unsigned int x = (unsigned int)u << 16;
    return __uint_as_float(x);
}
__device__ __forceinline__ bf16x8 ld8(const unsigned short* p) {   // 4B-aligned
    union { unsigned int u[4]; bf16x8 v; } t;
    const unsigned int* q = reinterpret_cast<const unsigned int*>(p);
    t.u[0] = q[0]; t.u[1] = q[1]; t.u[2] = q[2]; t.u[3] = q[3];
    return t.v;
}

// ---------------- DCT matrix init -> bf16 direct + transposed ----------------
__global__ __launch_bounds__(BLK) void k_dct_init(bft* __restrict__ dctb,
                                                  bft* __restrict__ dctTb) {
    int idx = blockIdx.x * BLK + threadIdx.x;
    if (idx >= L * L) return;
    int p = idx / L, h = idx - p * L;
    double v = (p == 0) ? sqrt(1.0 / L)
                        : cos(PI_D * p * (2 * h + 1) / (2.0 * L)) * sqrt(2.0 / L);
    bft bv = __float2bfloat16((float)v);
    dctb[p * L + h] = bv;
    dctTb[h * L + p] = bv;
}

// ---------------- fp32 weight -> bf16 with zero pad --------------------------
__global__ __launch_bounds__(BLK) void k_cvt(const float* __restrict__ src,
                                             bft* __restrict__ dst,
                                             int Mr, int Kr, int Kp) {
    int idx = blockIdx.x * BLK + threadIdx.x;   // [0, Mp*Kp)
    int m = idx / Kp, k = idx - m * Kp;
    float v = (m < Mr && k < Kr) ? src[(size_t)m * Kr + k] : 0.f;
    dst[idx] = __float2bfloat16(v);
}

// ---------------- LayerNorm over channel dim (per batch) ---------------------
template <typename TI>
__global__ __launch_bounds__(BLK) void k_ln(const TI* __restrict__ x,
                                            const float* __restrict__ w,
                                            const float* __restrict__ b,
                                            bft* __restrict__ out) {
    int s = blockIdx.x * BLK + threadIdx.x;   // [0, S)
    const TI* xp = x + s;
    float sum = 0.f, sq = 0.f;
    for (int c = 0; c < Cc; ++c) {
        float v = ldf(xp + (size_t)c * S);
        sum += v; sq += v * v;
    }
    float mu = sum * (1.f / Cc);
    float var = sq * (1.f / Cc) - mu * mu;
    float r = rsqrtf(var + 1e-5f);
    for (int c = 0; c < Cc; ++c) {
        float v = ldf(xp + (size_t)c * S);
        stf(out + s + (size_t)c * S, (v - mu) * r * w[c] + b[c]);
    }
}

// =============================================================================
// Unified MFMA bf16 GEMM. Block = (WR*FM*16) x (WC*FN*16), 4 waves (WR x WC),
// BK=32. All operands bf16 (weights pre-converted).
//   BMODE: 0 = bf16 [k][n] strideB (+zB batch); 1 = FFN strip gather from [k][S]
//   OMODE: 0 = linear; 1 = FFN strip scatter; 2 = window-tiled -> spatial
// =============================================================================
template <int WR, int WC, int FM, int FN, int BMODE, int OMODE,
          bool HASBIAS, bool HASRES, typename OutT, typename ResT>
__global__ __launch_bounds__(256) void k_mm(
    const bft* __restrict__ A, int strideA, int Mreal, long zA,
    const bft* __restrict__ B, int strideB, long zB,
    OutT* __restrict__ Out, int strideO, long zO,
    const float* __restrict__ bias,
    const ResT* __restrict__ Res, long zR,
    int K, int w0) {
    constexpr int BM = WR * FM * 16, BN = WC * FN * 16;
    __shared__ unsigned short Al[BM][40];
    __shared__ unsigned short Bl[BN][40];
    const int tid = threadIdx.x;
    const int n0 = blockIdx.x * BN, m0 = blockIdx.y * BM, bz = blockIdx.z;
    const int lane = tid & 63, wv = tid >> 6;
    const int wr = wv / WC, wc = wv % WC;
    const int l15 = lane & 15, l4 = lane >> 4;
    f32x4 acc[FM][FN] = {};

    constexpr int AE = BM / 8;
    constexpr int TPR = 256 / BM;
    const int arow = tid / TPR, akc = (tid % TPR) * AE;
    int bn, bk; bool bact = true;
    if constexpr (BN == 128) { bn = tid & 127; bk = (tid >> 7) * 16; }
    else                     { bn = tid; bk = 0; bact = (tid < BN); }
    constexpr int BE = (BN == 128) ? 16 : 32;
    int b_h = 0, b_wg = 0; bool b_ok = true;
    if constexpr (BMODE == 1) {
        int gn = n0 + bn; b_h = gn / PW; int wl = gn - b_h * PW; b_wg = w0 - 1 + wl;
        b_ok = (b_wg >= 0 && b_wg < L);
    }

    const bft* Ab = A + (size_t)bz * zA;
    const bft* Bb = B + (size_t)bz * zB;
    int gm = m0 + arow; if (gm >= Mreal) gm = Mreal - 1;

    for (int k0 = 0; k0 < K; k0 += 32) {
        {
            const bft* src = Ab + (size_t)gm * strideA + k0 + akc;
#pragma unroll
            for (int q = 0; q < AE / 8; ++q)
                *reinterpret_cast<uint4*>(&Al[arow][akc + 8 * q]) =
                    *reinterpret_cast<const uint4*>(src + 8 * q);
        }
        if (bact) {
            unsigned short v[BE];
            if constexpr (BMODE == 0) {
                const bft* src = Bb + (size_t)(k0 + bk) * strideB + n0 + bn;
#pragma unroll
                for (int e = 0; e < BE; ++e) v[e] = bfu(src + (size_t)e * strideB);
            } else {
                const bft* src = Bb + (size_t)(k0 + bk) * S + (size_t)b_h * L + b_wg;
#pragma unroll
                for (int e = 0; e < BE; ++e)
                    v[e] = b_ok ? bfu(src + (size_t)e * S) : (unsigned short)0;
            }
#pragma unroll
            for (int q = 0; q < BE / 8; ++q)
                *reinterpret_cast<uint4*>(&Bl[bn][bk + 8 * q]) =
                    *reinterpret_cast<uint4*>(&v[8 * q]);
        }
        __syncthreads();
        bf16x8 af[FM], bf[FN];
#pragma unroll
        for (int i = 0; i < FM; ++i)
            af[i] = *reinterpret_cast<const bf16x8*>(
                &Al[wr * FM * 16 + i * 16 + l15][l4 * 8]);
#pragma unroll
        for (int j = 0; j < FN; ++j)
            bf[j] = *reinterpret_cast<const bf16x8*>(
                &Bl[wc * FN * 16 + j * 16 + l15][l4 * 8]);
#pragma unroll
        for (int i = 0; i < FM; ++i)
#pragma unroll
            for (int j = 0; j < FN; ++j)
                acc[i][j] = __builtin_amdgcn_mfma_f32_16x16x32_bf16(
                    af[i], bf[j], acc[i][j], 0, 0, 0);
        __syncthreads();
    }
#pragma unroll
    for (int i = 0; i < FM; ++i) {
        int mB = m0 + wr * FM * 16 + i * 16 + l4 * 4;
#pragma unroll
        for (int j = 0; j < FN; ++j) {
            int n = n0 + wc * FN * 16 + j * 16 + l15;
#pragma unroll
            for (int r = 0; r < 4; ++r) {
                int m = mB + r;
                if (m >= Mreal) continue;
                float vv = acc[i][j][r];
                if constexpr (HASBIAS) vv += bias[m];
                size_t idx;
                if constexpr (OMODE == 0)
                    idx = (size_t)bz * zO + (size_t)m * strideO + n;
                else if constexpr (OMODE == 1) {
                    int h = n / SW, wl = n - h * SW;
                    idx = (size_t)m * S + (size_t)h * L + w0 + wl;
                } else {
                    int win = n >> 6, e = n & 63;
                    int hh = ((win / 24) << 3) + (e >> 3);
                    int ww = ((win % 24) << 3) + (e & 7);
                    idx = (size_t)m * S + (size_t)hh * L + ww;
                }
                if constexpr (HASRES) vv += ldf(Res + ((OMODE == 0)
                                  ? ((size_t)bz * zR + (size_t)m * strideO + n) : idx));
                stf(Out + idx, vv);
            }
        }
    }
}

// ---------------- depthwise 3x3 (8 outputs/thread) -> window-tiled -----------
__global__ __launch_bounds__(BLK) void k_dwconv(const bft* __restrict__ in,
                                                const float* __restrict__ wt,
                                                bft* __restrict__ out) {
    int t = blockIdx.x * BLK + threadIdx.x;      // [0, Cc*S/8)
    int ch = t / (S / 8);
    int rem = t - ch * (S / 8);
    int h = rem / 24, wb = (rem - h * 24) * 8;
    const float* wp = wt + (size_t)ch * 9;
    const bft* ip = in + (size_t)ch * S;
    float acc[8] = {};
#pragma unroll
    for (int dy = -1; dy <= 1; ++dy) {
        int hh = h + dy;
        if (hh < 0 || hh >= L) continue;
        const bft* rp = ip + hh * L + wb;
        float e[10];
        uint4 mid = *reinterpret_cast<const uint4*>(rp);
        const unsigned short* ms = reinterpret_cast<const unsigned short*>(&mid);
#pragma unroll
        for (int q = 0; q < 8; ++q) e[q + 1] = bu2f(ms[q]);
        e[0] = (wb > 0) ? ldf(rp - 1) : 0.f;
        e[9] = (wb + 8 < L) ? ldf(rp + 8) : 0.f;
        float c0 = wp[(dy + 1) * 3], c1 = wp[(dy + 1) * 3 + 1], c2 = wp[(dy + 1) * 3 + 2];
#pragma unroll
        for (int q = 0; q < 8; ++q)
            acc[q] += c0 * e[q] + c1 * e[q + 1] + c2 * e[q + 2];
    }
    int win = (h >> 3) * 24 + (wb >> 3);
    int e0 = (h & 7) * 8;
    unsigned short ov[8];
#pragma unroll
    for (int q = 0; q < 8; ++q) ov[q] = f2bfu(acc[q]);
    *reinterpret_cast<uint4*>(out + (size_t)ch * S + win * 64 + e0) =
        *reinterpret_cast<uint4*>(ov);
}

// ---------------- window channel attention via MFMA (window-tiled in/out) ----
// One wave per (window, head); 4 waves/block. q/k/v in per-wave LDS [32][66].
__global__ __launch_bounds__(256) void k_attn_mfma(const bft* __restrict__ QW,
                                                   const bft* __restrict__ KW,
                                                   const bft* __restrict__ VW,
                                                   const float* __restrict__ temp,
                                                   bft* __restrict__ outp) {
    __shared__ unsigned short qls[4][32 * 66];   // also reused for P after QK^T
    __shared__ unsigned short kls[4][32 * 66];
    __shared__ unsigned short vls[4][32 * 66];
    __shared__ float rqs[4][32], rks[4][32];
    const int tid = threadIdx.x;
    const int wv = tid >> 6, lane = tid & 63;
    const int win = blockIdx.x * 4 + wv;
    const int hd = blockIdx.y;
    const int l15 = lane & 15, l4 = lane >> 4;
    unsigned short* ql = qls[wv];
    unsigned short* kl = kls[wv];
    unsigned short* vl = vls[wv];
    const size_t base = (size_t)(hd * 32) * S + (size_t)win * 64;

    // ---- stage q,k,v: coalesced uint4 reads, 4x b32 LDS writes (stride 66) --
#pragma unroll
    for (int i = 0; i < 4; ++i) {
        int c = i * 8 + (lane >> 3), e0 = (lane & 7) * 8;
        size_t g = base + (size_t)c * S + e0;
        uint4 vq = *reinterpret_cast<const uint4*>(QW + g);
        uint4 vk = *reinterpret_cast<const uint4*>(KW + g);
        uint4 vvv = *reinterpret_cast<const uint4*>(VW + g);
        unsigned int* dq = reinterpret_cast<unsigned int*>(&ql[c * 66 + e0]);
        unsigned int* dk = reinterpret_cast<unsigned int*>(&kl[c * 66 + e0]);
        unsigned int* dv = reinterpret_cast<unsigned int*>(&vl[c * 66 + e0]);
        dq[0] = vq.x; dq[1] = vq.y; dq[2] = vq.z; dq[3] = vq.w;
        dk[0] = vk.x; dk[1] = vk.y; dk[2] = vk.z; dk[3] = vk.w;
        dv[0] = vvv.x; dv[1] = vvv.y; dv[2] = vvv.z; dv[3] = vvv.w;
    }
    __syncthreads();
    // ---- l2norm factors: lanes 0..31 -> q rows, 32..63 -> k rows -------------
    {
        int row = lane & 31;
        const unsigned short* src = (lane < 32) ? ql : kl;
        float s = 0.f;
#pragma unroll
        for (int w = 0; w < 32; ++w) {
            unsigned int d = *reinterpret_cast<const unsigned int*>(&src[row * 66 + 2 * w]);
            float a = bu2f((unsigned short)(d & 0xffff));
            float b = bu2f((unsigned short)(d >> 16));
            s += a * a + b * b;
        }
        float r = 1.f / fmaxf(sqrtf(s), 1e-12f);
        if (lane < 32) rqs[wv][row] = r; else rks[wv][row] = r;
    }
    __syncthreads();
    // ---- QK^T: 8 MFMA (2i x 2j x 2 k-steps) ---------------------------------
    f32x4 at[2][2] = {};
#pragma unroll
    for (int ks = 0; ks < 2; ++ks) {
        bf16x8 aq[2], bk[2];
#pragma unroll
        for (int i = 0; i < 2; ++i)
            aq[i] = ld8(&ql[(i * 16 + l15) * 66 + ks * 32 + l4 * 8]);
#pragma unroll
        for (int j = 0; j < 2; ++j)
            bk[j] = ld8(&kl[(j * 16 + l15) * 66 + ks * 32 + l4 * 8]);
#pragma unroll
        for (int i = 0; i < 2; ++i)
#pragma unroll
            for (int j = 0; j < 2; ++j)
                at[i][j] = __builtin_amdgcn_mfma_f32_16x16x32_bf16(
                    aq[i], bk[j], at[i][j], 0, 0, 0);
    }
    // ---- scale (temp * rq * rk) + wave-parallel softmax over d (cols) -------
    float tpr = temp[hd];
    float rk0 = rks[wv][l15] * tpr, rk1 = rks[wv][16 + l15] * tpr;
    float pr[2][2][4];
#pragma unroll
    for (int i = 0; i < 2; ++i)
#pragma unroll
        for (int r = 0; r < 4; ++r) {
            int c = i * 16 + l4 * 4 + r;
            float rq = rqs[wv][c];
            float v0 = at[i][0][r] * rq * rk0;
            float v1 = at[i][1][r] * rq * rk1;
            float mx = fmaxf(v0, v1);
#pragma unroll
            for (int m = 1; m < 16; m <<= 1) mx = fmaxf(mx, __shfl_xor(mx, m));
            v0 = __expf(v0 - mx);
            v1 = __expf(v1 - mx);
            float sm = v0 + v1;
#pragma unroll
            for (int m = 1; m < 16; m <<= 1) sm += __shfl_xor(sm, m);
            float inv = 1.f / sm;
            pr[i][0][r] = v0 * inv;
            pr[i][1][r] = v1 * inv;
        }
    __syncthreads();   // all QK^T LDS reads done before q region is reused
    // ---- store P (bf16) into dead q region: p[c][d], stride 34 --------------
    unsigned short* pl = ql;
#pragma unroll
    for (int i = 0; i < 2; ++i)
#pragma unroll
        for (int j = 0; j < 2; ++j)
#pragma unroll
            for (int r = 0; r < 4; ++r)
                pl[(i * 16 + l4 * 4 + r) * 34 + j * 16 + l15] = f2bfu(pr[i][j][r]);
    __syncthreads();
    // ---- PV: 8 MFMA (2i x 4j, K=32) -----------------------------------------
    bf16x8 ap[2];
#pragma unroll
    for (int i = 0; i < 2; ++i)
        ap[i] = ld8(&pl[(i * 16 + l15) * 34 + l4 * 8]);
    f32x4 o[2][4] = {};
#pragma unroll
    for (int j = 0; j < 4; ++j) {
        unsigned short tv[8];
#pragma unroll
        for (int q = 0; q < 8; ++q)
            tv[q] = vl[(l4 * 8 + q) * 66 + j * 16 + l15];
        bf16x8 bv = *reinterpret_cast<bf16x8*>(tv);
#pragma unroll
        for (int i = 0; i < 2; ++i)
            o[i][j] = __builtin_amdgcn_mfma_f32_16x16x32_bf16(ap[i], bv, o[i][j], 0, 0, 0);
    }
    // ---- write out[c][e] window-tiled ---------------------------------------
#pragma unroll
    for (int i = 0; i < 2; ++i)
#pragma unroll
        for (int j = 0; j < 4; ++j)
#pragma unroll
            for (int r = 0; r < 4; ++r) {
                int c = i * 16 + l4 * 4 + r, e = j * 16 + l15;
                stf(outp + base + (size_t)c * S + e, o[i][j][r]);
            }
}

// ---------------- FFN gate on strip (vectorized, 8 outputs/thread) -----------
__global__ __launch_bounds__(BLK) void k_gate(const bft* __restrict__ f,
                                              const float* __restrict__ wt,
                                              bft* __restrict__ g) {
    const int NS = L * PW, NG = L * SW;  // 9600, 9216
    int t = blockIdx.x * BLK + threadIdx.x;       // HID * L * 6
    int c = t / (L * 6);
    int rr = t - c * (L * 6);
    int h = rr / 6, wl0 = (rr - h * 6) * 8;
    const bft* f1 = f + (size_t)c * NS;
    const bft* f2 = f + (size_t)(c + HID) * NS;
    float w1[9], w2[9];
#pragma unroll
    for (int i = 0; i < 9; ++i) {
        w1[i] = wt[(size_t)c * 9 + i];
        w2[i] = wt[((size_t)c + HID) * 9 + i];
    }
    float a1[8], a2[8];
#pragma unroll
    for (int j = 0; j < 8; ++j) { a1[j] = 0.f; a2[j] = 0.f; }
#pragma unroll
    for (int dy = 0; dy < 3; ++dy) {
        int hh = h + dy - 1;
        if (hh < 0 || hh >= L) continue;
        float e1[10], e2[10];
        const unsigned int* p1 =
            reinterpret_cast<const unsigned int*>(f1 + (size_t)hh * PW + wl0);
        const unsigned int* p2 =
            reinterpret_cast<const unsigned int*>(f2 + (size_t)hh * PW + wl0);
#pragma unroll
        for (int q = 0; q < 5; ++q) {
            unsigned int d1 = p1[q], d2 = p2[q];
            e1[2 * q]     = bu2f((unsigned short)(d1 & 0xffff));
            e1[2 * q + 1] = bu2f((unsigned short)(d1 >> 16));
            e2[2 * q]     = bu2f((unsigned short)(d2 & 0xffff));
            e2[2 * q + 1] = bu2f((unsigned short)(d2 >> 16));
        }
#pragma unroll
        for (int dx = 0; dx < 3; ++dx) {
            float ww1 = w1[dy * 3 + dx], ww2 = w2[dy * 3 + dx];
#pragma unroll
            for (int j = 0; j < 8; ++j) {
                a1[j] += ww1 * e1[j + dx];
                a2[j] += ww2 * e2[j + dx];
            }
        }
    }
    unsigned short ov[8];
#pragma unroll
    for (int j = 0; j < 8; ++j) {
        float ge = 0.5f * a1[j] * (1.f + erff(a1[j] * 0.70710678118654752f));
        ov[j] = f2bfu(ge * a2[j]);
    }
    *reinterpret_cast<uint4*>(g + (size_t)c * NG + (size_t)h * SW + wl0) =
        *reinterpret_cast<uint4*>(ov);
}

// -----------------------------------------------------------------------------
extern "C" void kernel_launch(void* const* d_in, const int* in_sizes, int n_in,
                              void* d_out, int out_size, void* d_ws, size_t ws_size,
                              hipStream_t stream) {
    const float* x      = (const float*)d_in[0];
    const float* n1w    = (const float*)d_in[1];
    const float* n1b    = (const float*)d_in[2];
    const float* w_qkv  = (const float*)d_in[3];
    const float* w_dw   = (const float*)d_in[4];
    const float* temp   = (const float*)d_in[5];
    const float* w_proj = (const float*)d_in[6];
    const float* b_proj = (const float*)d_in[7];
    const float* n2w    = (const float*)d_in[8];
    const float* n2b    = (const float*)d_in[9];
    const float* w_in   = (const float*)d_in[10];
    const float* w_dwf  = (const float*)d_in[11];
    const float* w_out  = (const float*)d_in[12];
    float* outp = (float*)d_out;

    // workspace layout: 100,122,624 bytes
    const size_t DCT_B = 147456;                       // dctb + dctTb (bf16)
    const size_t CS    = (size_t)Cc * S;
    const size_t X1_B  = (size_t)Bn * CS * 2;
    const size_t P_B   = CS * 2;
    const size_t WB_B  = 884736;                       // bf16 weight cache
    const size_t NEED  = DCT_B + X1_B + 2 * P_B + (size_t)3 * CS * 2 + WB_B;
    if (ws_size < NEED) return;

    char* p = (char*)d_ws;
    bft* dctb  = (bft*)p;                  // [192][192]
    bft* dctTb = dctb + L * L;             // [192][192]
    p += DCT_B;
    bft* X1    = (bft*)p;                  p += X1_B;
    bft* Pb    = (bft*)p;                  p += P_B;
    bft* Qb    = (bft*)p;                  p += P_B;
    bft* QKV   = (bft*)p;                  p += 3 * CS * 2;
    bft* w_qkv_b = (bft*)p;                // 576*192
    bft* w_proj_b = w_qkv_b + 576 * 192;   // 192*192
    bft* w_in_b  = w_proj_b + 192 * 192;   // 1024*192 (pad M)
    bft* w_out_b = w_in_b + 1024 * 192;    // 192*512 (pad K)
    bft* fbuf  = QKV;                      // 1024 x 9600
    bft* gstrip = Qb;                      // 512 x 9216

    // prep: dct + weight conversion (once)
    k_dct_init<<<144, BLK, 0, stream>>>(dctb, dctTb);
    k_cvt<<<432, BLK, 0, stream>>>(w_qkv, w_qkv_b, 576, 192, 192);
    k_cvt<<<144, BLK, 0, stream>>>(w_proj, w_proj_b, 192, 192, 192);
    k_cvt<<<768, BLK, 0, stream>>>(w_in, w_in_b, 1020, 192, 192);
    k_cvt<<<384, BLK, 0, stream>>>(w_out, w_out_b, 192, 510, 512);

    for (int b = 0; b < Bn; ++b) {
        const float* xb = x + (size_t)b * CS;
        bft* x1b = X1 + (size_t)b * CS;
        k_ln<float><<<S / BLK, BLK, 0, stream>>>(xb, n1w, n1b, Pb);
        // t = Mh @ Y (batched over c)  [64x192 tile]
        k_mm<1, 4, 4, 3, 0, 0, false, false, bft, float><<<dim3(1, 3, Cc), 256, 0, stream>>>(
            dctb, L, L, 0,  Pb, L, S,  Qb, L, S,  nullptr, nullptr, 0,  L, 0);
        // yd = T @ Mw^T (flattened M=36864)
        k_mm<1, 4, 4, 3, 0, 0, false, false, bft, float><<<dim3(1, 576, 1), 256, 0, stream>>>(
            Qb, L, S * Cc / L, 0,  dctTb, L, 0,  Pb, L, 0,  nullptr, nullptr, 0,  L, 0);
        // qkv = W_qkv @ yd  [128x128 tile]
        k_mm<2, 2, 4, 4, 0, 0, false, false, bft, float><<<dim3(288, 5, 1), 256, 0, stream>>>(
            w_qkv_b, Cc, 576, 0,  Pb, S, 0,  QKV, S, 0,  nullptr, nullptr, 0,  Cc, 0);
        // depthwise 3x3 -> window-tiled: q->Pb, k->Qb, v->QKV[0:CS]
        k_dwconv<<<(Cc * S / 8) / BLK, BLK, 0, stream>>>(QKV, w_dw, Pb);
        k_dwconv<<<(Cc * S / 8) / BLK, BLK, 0, stream>>>(QKV + CS, w_dw + Cc * 9, Qb);
        k_dwconv<<<(Cc * S / 8) / BLK, BLK, 0, stream>>>(QKV + 2 * CS, w_dw + 2 * Cc * 9, QKV);
        // attention (MFMA) -> QKV[CS:2CS] (window-tiled)
        k_attn_mfma<<<dim3(144, 6), 256, 0, stream>>>(Pb, Qb, QKV, temp, QKV + CS);
        // proj + bias, window decode -> Pb spatial(dct coords)
        k_mm<2, 2, 4, 4, 0, 2, true, false, bft, float><<<dim3(288, 2, 1), 256, 0, stream>>>(
            w_proj_b, Cc, Cc, 0,  QKV + CS, S, 0,  Pb, S, 0,  b_proj, nullptr, 0,  Cc, 0);
        // u = P @ Mw (flattened)
        k_mm<1, 4, 4, 3, 0, 0, false, false, bft, float><<<dim3(1, 576, 1), 256, 0, stream>>>(
            Pb, L, S * Cc / L, 0,  dctb, L, 0,  Qb, L, 0,  nullptr, nullptr, 0,  L, 0);
        // x1 = Mh^T @ U + x (batched over c)
        k_mm<1, 4, 4, 3, 0, 0, false, true, bft, float><<<dim3(1, 3, Cc), 256, 0, stream>>>(
            dctTb, L, L, 0,  Qb, L, S,  x1b, L, S,  nullptr, xb, S,  L, 0);
    }
    for (int b = 0; b < Bn; ++b) {
        bft* x1b = X1 + (size_t)b * CS;
        float* outb = outp + (size_t)b * CS;
        k_ln<bft><<<S / BLK, BLK, 0, stream>>>(x1b, n2w, n2b, Pb);
        for (int st = 0; st < 4; ++st) {
            int w0 = st * SW;
            // f = W_in @ z (strip gather)
            k_mm<2, 2, 4, 4, 1, 0, false, false, bft, float><<<dim3(75, 8, 1), 256, 0, stream>>>(
                w_in_b, Cc, 1024, 0,  Pb, S, 0,  fbuf, L * PW, 0,
                nullptr, nullptr, 0,  Cc, w0);
            // gated dwconv + GELU
            k_gate<<<(HID * L * 6) / BLK, BLK, 0, stream>>>(fbuf, w_dwf, gstrip);
            // out = W_out @ g + x1 (strip scatter, fp32 out)
            k_mm<2, 2, 4, 4, 0, 1, false, true, float, bft><<<dim3(72, 2, 1), 256, 0, stream>>>(
                w_out_b, 512, Cc, 0,  gstrip, L * SW, 0,  outb, 0, 0,
                nullptr, x1b, 0,  512, w0);
        }
    }
}